// Round 1
// baseline (6496.638 us; speedup 1.0000x reference)
//
// QANet-style fused attention block, MI355X fp32 baseline.
// Stages: s=s0+s1+s2+bias -> masked softmaxes -> small batched GEMMs ->
// MHA1 probs (4 heads) -> concat+LN (x->d_out, y->ws) -> two big NT GEMMs
// (qh2/kh2) -> fused 24-head scores/softmax/mean -> col softmax -> ss1@y + x.
// Workspace: 243.3 MB (early buffers aliased under qh2 region).
#include <hip/hip_runtime.h>

#define B_ 8
#define CL 512
#define QL 64
#define H_ 768
#define E2 4608
#define NH2 24
#define HD 192
#define NEGV -1e30f
#define SCALE 0.07216878364870323f  // 1/sqrt(192)

__device__ __forceinline__ float wave_max(float v) {
#pragma unroll
  for (int m = 32; m >= 1; m >>= 1) v = fmaxf(v, __shfl_xor(v, m, 64));
  return v;
}
__device__ __forceinline__ float wave_sum(float v) {
#pragma unroll
  for (int m = 32; m >= 1; m >>= 1) v += __shfl_xor(v, m, 64);
  return v;
}

// out[r] = dot(in[r, :K], w[:K]); one wave per row.
__global__ __launch_bounds__(256) void k_rowdot(const float* __restrict__ in,
                                                const float* __restrict__ w,
                                                float* __restrict__ out, int K) {
  int t = threadIdx.x, lane = t & 63, wv = t >> 6;
  int row = blockIdx.x * 4 + wv;
  const float* ip = in + (size_t)row * K;
  float s = 0.f;
  for (int j = lane; j < K; j += 64) s += ip[j] * w[j];
  s = wave_sum(s);
  if (lane == 0) out[row] = s;
}

// s[b,c,q] = s0[b,c] + s1[b,q] + sum_h c[b,c,h]*cqw[h]*q[b,q,h] + bias
__global__ __launch_bounds__(256) void k_s_assemble(
    const float* __restrict__ c, const float* __restrict__ q,
    const float* __restrict__ cqw, const float* __restrict__ s0,
    const float* __restrict__ s1, const float* __restrict__ bias,
    float* __restrict__ s) {
  int b = blockIdx.y, c0 = blockIdx.x * 32;
  int t = threadIdx.x, qq = t & 63, grp = t >> 6;
  __shared__ float qs[64][33];
  __shared__ float cs[32][33];
  float acc[8] = {};
  int qr = t >> 2, qc = (t & 3) * 8;
  for (int k0 = 0; k0 < H_; k0 += 32) {
    float qbuf[8], cbuf[8] = {};
    {
      const float4* qp = (const float4*)(q + (size_t)(b * QL + qr) * H_ + k0 + qc);
      float4 q0 = qp[0], q1 = qp[1];
      qbuf[0]=q0.x; qbuf[1]=q0.y; qbuf[2]=q0.z; qbuf[3]=q0.w;
      qbuf[4]=q1.x; qbuf[5]=q1.y; qbuf[6]=q1.z; qbuf[7]=q1.w;
    }
    if (t < 128) {
      int cr = t >> 2, cc = (t & 3) * 8;
      const float4* cp = (const float4*)(c + (size_t)(b * CL + c0 + cr) * H_ + k0 + cc);
      float4 c0v = cp[0], c1v = cp[1];
      float tmp[8] = {c0v.x,c0v.y,c0v.z,c0v.w,c1v.x,c1v.y,c1v.z,c1v.w};
#pragma unroll
      for (int j = 0; j < 8; ++j) cbuf[j] = tmp[j] * cqw[k0 + cc + j];
    }
    __syncthreads();
#pragma unroll
    for (int j = 0; j < 8; ++j) qs[qr][qc + j] = qbuf[j];
    if (t < 128) {
      int cr = t >> 2, cc = (t & 3) * 8;
#pragma unroll
      for (int j = 0; j < 8; ++j) cs[cr][cc + j] = cbuf[j];
    }
    __syncthreads();
#pragma unroll
    for (int kk = 0; kk < 32; ++kk) {
      float qv = qs[qq][kk];
#pragma unroll
      for (int i = 0; i < 8; ++i) acc[i] += cs[grp * 8 + i][kk] * qv;
    }
    __syncthreads();
  }
  float s1v = s1[b * QL + qq], b0 = bias[0];
#pragma unroll
  for (int i = 0; i < 8; ++i) {
    int cc = c0 + grp * 8 + i;
    s[(size_t)(b * CL + cc) * QL + qq] = acc[i] + s0[b * CL + cc] + s1v + b0;
  }
}

// masked softmax over last axis (len 64), mask = q_mask[b, q]; 1 wave/row.
__global__ __launch_bounds__(256) void k_rowsm64(const float* __restrict__ in,
                                                 const int* __restrict__ qmask,
                                                 float* __restrict__ out) {
  int t = threadIdx.x, lane = t & 63, wv = t >> 6;
  int row = blockIdx.x * 4 + wv;  // b*CL + c
  int b = row >> 9;
  float x = in[(size_t)row * QL + lane];
  float v = qmask[b * QL + lane] ? x : NEGV;
  float M = wave_max(v);
  float e = expf(v - M);
  float S = wave_sum(e);
  out[(size_t)row * QL + lane] = e / S;
}

// masked softmax over axis-1 (rows, len CL=512) for each (b, col); mask=c_mask[b,r].
__global__ __launch_bounds__(256) void k_colsm(const float* __restrict__ in,
                                               const int* __restrict__ cmask,
                                               float* __restrict__ out, int C) {
  int b = blockIdx.y, col = blockIdx.x, t = threadIdx.x;
  int lane = t & 63, wv = t >> 6;
  const float* ip = in + (size_t)b * CL * C + col;
  float* op = out + (size_t)b * CL * C + col;
  const int* mp = cmask + b * CL;
  float v0 = mp[t] ? ip[(size_t)t * C] : NEGV;
  float v1 = mp[t + 256] ? ip[(size_t)(t + 256) * C] : NEGV;
  __shared__ float red[4];
  float m = wave_max(fmaxf(v0, v1));
  if (lane == 0) red[wv] = m;
  __syncthreads();
  float M = fmaxf(fmaxf(red[0], red[1]), fmaxf(red[2], red[3]));
  __syncthreads();
  float e0 = expf(v0 - M), e1 = expf(v1 - M);
  float s = wave_sum(e0 + e1);
  if (lane == 0) red[wv] = s;
  __syncthreads();
  float S = red[0] + red[1] + red[2] + red[3];
  op[(size_t)t * C] = e0 / S;
  op[(size_t)(t + 256) * C] = e1 / S;
}

// Batched GEMM: out[b,m,n] = sum_k A[b,(ta? k*M+m : m*K+k)] * Bm[b,k*N+n]
// (+ out if addout). Tile 32m x 64n x 32k, 256 thr, 8 rows/thread.
__global__ __launch_bounds__(256) void k_gemm_bt(const float* __restrict__ A,
                                                 const float* __restrict__ Bm,
                                                 float* __restrict__ out, int M,
                                                 int K, int N, int ta, int addout) {
  int b = blockIdx.z;
  int n0 = blockIdx.x * 64, m0 = blockIdx.y * 32;
  const float* Ab = A + (size_t)b * M * K;
  const float* Bb = Bm + (size_t)b * K * N;
  float* Ob = out + (size_t)b * M * N;
  int t = threadIdx.x, lane = t & 63, mg = (t >> 6) * 8;
  __shared__ float As[32][36];
  __shared__ float Bs[32][64];
  float acc[8] = {};
  for (int k0 = 0; k0 < K; k0 += 32) {
    float4 av; float4 bv0, bv1;
    if (!ta) {
      int r = t >> 3, cc = (t & 7) * 4;
      av = *(const float4*)(Ab + (size_t)(m0 + r) * K + k0 + cc);
    } else {
      int kk = t >> 3, r4 = (t & 7) * 4;
      av = *(const float4*)(Ab + (size_t)(k0 + kk) * M + m0 + r4);
    }
    {
      int kk = t >> 3, n8 = (t & 7) * 8;
      const float4* bp = (const float4*)(Bb + (size_t)(k0 + kk) * N + n0 + n8);
      bv0 = bp[0]; bv1 = bp[1];
    }
    __syncthreads();
    if (!ta) {
      int r = t >> 3, cc = (t & 7) * 4;
      As[r][cc] = av.x; As[r][cc + 1] = av.y; As[r][cc + 2] = av.z; As[r][cc + 3] = av.w;
    } else {
      int kk = t >> 3, r4 = (t & 7) * 4;
      As[r4][kk] = av.x; As[r4 + 1][kk] = av.y; As[r4 + 2][kk] = av.z; As[r4 + 3][kk] = av.w;
    }
    {
      int kk = t >> 3, n8 = (t & 7) * 8;
      float tmp[8] = {bv0.x,bv0.y,bv0.z,bv0.w,bv1.x,bv1.y,bv1.z,bv1.w};
#pragma unroll
      for (int j = 0; j < 8; ++j) Bs[kk][n8 + j] = tmp[j];
    }
    __syncthreads();
#pragma unroll 4
    for (int kk = 0; kk < 32; ++kk) {
      float bv = Bs[kk][lane];
#pragma unroll
      for (int i = 0; i < 8; ++i) acc[i] += As[mg + i][kk] * bv;
    }
    __syncthreads();
  }
#pragma unroll
  for (int i = 0; i < 8; ++i) {
    size_t idx = (size_t)(m0 + mg + i) * N + n0 + lane;
    Ob[idx] = acc[i] + (addout ? Ob[idx] : 0.f);
  }
}

// NT weight GEMM: out[r,n] = sum_k A[r,k]*W[n,k] + bias[n].
// Tile 128r x 64n x 32k; 256 thr, 8x4 acc; LDS stored k-major for float4 reads.
__global__ __launch_bounds__(256) void k_gemm_nt(const float* __restrict__ A,
                                                 const float* __restrict__ W,
                                                 const float* __restrict__ bias,
                                                 float* __restrict__ out, int K,
                                                 int N) {
  int n0 = blockIdx.x * 64, m0 = blockIdx.y * 128;
  int t = threadIdx.x;
  __shared__ float At[32][128];
  __shared__ float Wt[32][64];
  float acc[8][4] = {};
  int ar = t >> 1, ac = (t & 1) * 16;
  int wr = t >> 2, wc = (t & 3) * 8;
  const float* Ap = A + (size_t)(m0 + ar) * K + ac;
  const float* Wp = W + (size_t)(n0 + wr) * K + wc;
  int mg = (t >> 4) * 8, ng = (t & 15) * 4;
  for (int k0 = 0; k0 < K; k0 += 32) {
    float4 a4[4], w4[2];
    {
      const float4* ap = (const float4*)(Ap + k0);
#pragma unroll
      for (int j = 0; j < 4; ++j) a4[j] = ap[j];
      const float4* wp = (const float4*)(Wp + k0);
      w4[0] = wp[0]; w4[1] = wp[1];
    }
    __syncthreads();
    {
      float ta[16] = {a4[0].x,a4[0].y,a4[0].z,a4[0].w, a4[1].x,a4[1].y,a4[1].z,a4[1].w,
                      a4[2].x,a4[2].y,a4[2].z,a4[2].w, a4[3].x,a4[3].y,a4[3].z,a4[3].w};
#pragma unroll
      for (int j = 0; j < 16; ++j) At[ac + j][ar] = ta[j];
      float tw[8] = {w4[0].x,w4[0].y,w4[0].z,w4[0].w, w4[1].x,w4[1].y,w4[1].z,w4[1].w};
#pragma unroll
      for (int j = 0; j < 8; ++j) Wt[wc + j][wr] = tw[j];
    }
    __syncthreads();
#pragma unroll
    for (int kk = 0; kk < 32; ++kk) {
      float4 wv = *(const float4*)&Wt[kk][ng];
      float4 a0 = *(const float4*)&At[kk][mg];
      float4 a1 = *(const float4*)&At[kk][mg + 4];
      float am[8] = {a0.x,a0.y,a0.z,a0.w,a1.x,a1.y,a1.z,a1.w};
      float wn[4] = {wv.x,wv.y,wv.z,wv.w};
#pragma unroll
      for (int i = 0; i < 8; ++i)
#pragma unroll
        for (int j = 0; j < 4; ++j) acc[i][j] += am[i] * wn[j];
    }
    __syncthreads();
  }
  float bv[4];
#pragma unroll
  for (int j = 0; j < 4; ++j) bv[j] = bias[n0 + ng + j];
#pragma unroll
  for (int i = 0; i < 8; ++i) {
    float4 o;
    o.x = acc[i][0] + bv[0]; o.y = acc[i][1] + bv[1];
    o.z = acc[i][2] + bv[2]; o.w = acc[i][3] + bv[3];
    *(float4*)(out + (size_t)(m0 + mg + i) * N + n0 + ng) = o;
  }
}

// MHA1 probs: scoat[b,c,q] = mean_h softmax_q(qh1[b,c,h]·kh1[b,q,h]/sqrt(192)).
// One block per (b,c); wave h computes one head (lane = q).
__global__ __launch_bounds__(256) void k_mha1(const float* __restrict__ qh,
                                              const float* __restrict__ kh,
                                              float* __restrict__ scoat) {
  int blk = blockIdx.x;  // b*CL + c
  int b = blk >> 9;
  int t = threadIdx.x, lane = t & 63, h = t >> 6;
  __shared__ float qrow[H_];
  __shared__ float probs[4][64];
#pragma unroll
  for (int j = 0; j < 3; ++j) qrow[t + 256 * j] = qh[(size_t)blk * H_ + t + 256 * j];
  __syncthreads();
  const float* kp = kh + (size_t)(b * QL + lane) * H_ + h * HD;
  const float* qp = &qrow[h * HD];
  float sc = 0.f;
#pragma unroll 4
  for (int k = 0; k < HD; ++k) sc += qp[k] * kp[k];
  sc *= SCALE;
  float M = wave_max(sc);
  float e = expf(sc - M);
  float S = wave_sum(e);
  probs[h][lane] = e / S;
  __syncthreads();
  if (t < 64)
    scoat[(size_t)blk * QL + t] =
        0.25f * (probs[0][t] + probs[1][t] + probs[2][t] + probs[3][t]);
}

// Fused 24-head scores + softmax + head-mean: ss[b,c,d].
// Block = (b, 16 c-rows). K=192 split across 4 waves; scores in registers.
__global__ __launch_bounds__(256) void k_ss(const float* __restrict__ qh,
                                            const float* __restrict__ kh,
                                            float* __restrict__ ss) {
  int b = blockIdx.y, c0 = blockIdx.x * 16;
  int t = threadIdx.x, lane = t & 63, wv = t >> 6;
  __shared__ float qt[16 * 192];
  __shared__ float kt[64 * 193];
  float* red = kt;  // alias: [4][16][64], protected by barriers
  float score[4][8];
  float macc[4][8];
#pragma unroll
  for (int i = 0; i < 4; ++i)
#pragma unroll
    for (int j = 0; j < 8; ++j) macc[i][j] = 0.f;
  for (int h = 0; h < NH2; ++h) {
    {  // stage q-tile (16 rows x 192)
      int r = t >> 4, cc = (t & 15) * 12;
      const float4* qp = (const float4*)(qh + (size_t)(b * CL + c0 + r) * E2 + h * HD + cc);
      float4 v0 = qp[0], v1 = qp[1], v2 = qp[2];
      float* dst = &qt[r * 192 + cc];
      dst[0]=v0.x; dst[1]=v0.y; dst[2]=v0.z; dst[3]=v0.w;
      dst[4]=v1.x; dst[5]=v1.y; dst[6]=v1.z; dst[7]=v1.w;
      dst[8]=v2.x; dst[9]=v2.y; dst[10]=v2.z; dst[11]=v2.w;
    }
    for (int d0 = 0; d0 < CL; d0 += 64) {
      {  // stage k-tile (64 rows x 192), stride 193 (bank-friendly)
        int dr = t >> 2, cc = (t & 3) * 48;
        const float4* kp = (const float4*)(kh + (size_t)(b * CL + d0 + dr) * E2 + h * HD + cc);
        float* dst = &kt[dr * 193 + cc];
#pragma unroll
        for (int j = 0; j < 12; ++j) {
          float4 v = kp[j];
          dst[j * 4] = v.x; dst[j * 4 + 1] = v.y; dst[j * 4 + 2] = v.z; dst[j * 4 + 3] = v.w;
        }
      }
      __syncthreads();
      float pacc[16];
#pragma unroll
      for (int r = 0; r < 16; ++r) pacc[r] = 0.f;
      const int kb = wv * 48;
      for (int kk = 0; kk < 48; kk += 4) {
        float kv0 = kt[lane * 193 + kb + kk];
        float kv1 = kt[lane * 193 + kb + kk + 1];
        float kv2 = kt[lane * 193 + kb + kk + 2];
        float kv3 = kt[lane * 193 + kb + kk + 3];
#pragma unroll
        for (int r = 0; r < 16; ++r) {
          const float* qp = &qt[r * 192 + kb + kk];
          pacc[r] += qp[0] * kv0 + qp[1] * kv1 + qp[2] * kv2 + qp[3] * kv3;
        }
      }
      __syncthreads();  // kt reads done -> red may overwrite
#pragma unroll
      for (int r = 0; r < 16; ++r) red[(wv * 16 + r) * 64 + lane] = pacc[r];
      __syncthreads();
      int ch = d0 >> 6;
#pragma unroll
      for (int i = 0; i < 4; ++i) {
        int r = wv + 4 * i;
        score[i][ch] = red[r * 64 + lane] + red[(16 + r) * 64 + lane] +
                       red[(32 + r) * 64 + lane] + red[(48 + r) * 64 + lane];
      }
      __syncthreads();  // red reads done before next kt stage
    }
    // softmax over d (512 = 8 chunks x 64 lanes) per row, accumulate mean/24
#pragma unroll
    for (int i = 0; i < 4; ++i) {
      float m = -1e30f;
#pragma unroll
      for (int j = 0; j < 8; ++j) m = fmaxf(m, score[i][j]);
      m = wave_max(m);
      float e[8], sl = 0.f;
#pragma unroll
      for (int j = 0; j < 8; ++j) {
        e[j] = expf((score[i][j] - m) * SCALE);
        sl += e[j];
      }
      float S = wave_sum(sl);
      float inv = 1.f / (S * 24.f);
#pragma unroll
      for (int j = 0; j < 8; ++j) macc[i][j] += e[j] * inv;
    }
  }
#pragma unroll
  for (int i = 0; i < 4; ++i) {
    int r = wv + 4 * i;
#pragma unroll
    for (int j = 0; j < 8; ++j)
      ss[(size_t)(b * CL + c0 + r) * CL + j * 64 + lane] = macc[i][j];
  }
}

// concat x = [c, a, c*a, c*b, scoat3, acoat] -> d_out; layernorm -> y.
__global__ __launch_bounds__(256) void k_xln(
    const float* __restrict__ c, const float* __restrict__ a,
    const float* __restrict__ bf, const float* __restrict__ s3,
    const float* __restrict__ ac, const float* __restrict__ gamma,
    const float* __restrict__ beta, float* __restrict__ xout,
    float* __restrict__ y) {
  int row = blockIdx.x, t = threadIdx.x, lane = t & 63, wv = t >> 6;
  size_t base = (size_t)row * H_;
  float xs[6][3];
  float sum = 0.f, sq = 0.f;
#pragma unroll
  for (int kk = 0; kk < 3; ++kk) {
    int j = t + kk * 256;
    float cv = c[base + j], av = a[base + j], bv = bf[base + j];
    float sv = s3[base + j], av2 = ac[base + j];
    xs[0][kk] = cv; xs[1][kk] = av; xs[2][kk] = cv * av;
    xs[3][kk] = cv * bv; xs[4][kk] = sv; xs[5][kk] = av2;
  }
#pragma unroll
  for (int s = 0; s < 6; ++s)
#pragma unroll
    for (int kk = 0; kk < 3; ++kk) {
      sum += xs[s][kk];
      sq += xs[s][kk] * xs[s][kk];
    }
  sum = wave_sum(sum);
  sq = wave_sum(sq);
  __shared__ float red[4][2];
  if (lane == 0) { red[wv][0] = sum; red[wv][1] = sq; }
  __syncthreads();
  float TS = red[0][0] + red[1][0] + red[2][0] + red[3][0];
  float TQ = red[0][1] + red[1][1] + red[2][1] + red[3][1];
  float mu = TS * (1.f / (float)E2);
  float var = TQ * (1.f / (float)E2) - mu * mu;
  float rstd = rsqrtf(var + 1e-5f);
  size_t obase = (size_t)row * E2;
#pragma unroll
  for (int s = 0; s < 6; ++s)
#pragma unroll
    for (int kk = 0; kk < 3; ++kk) {
      int col = s * H_ + t + kk * 256;
      float xv = xs[s][kk];
      xout[obase + col] = xv;
      y[obase + col] = (xv - mu) * rstd * gamma[col] + beta[col];
    }
}

extern "C" void kernel_launch(void* const* d_in, const int* in_sizes, int n_in,
                              void* d_out, int out_size, void* d_ws,
                              size_t ws_size, hipStream_t stream) {
  const float* c = (const float*)d_in[0];
  const float* q = (const float*)d_in[1];
  const int* c_mask = (const int*)d_in[2];
  const int* q_mask = (const int*)d_in[3];
  const float* c_weight = (const float*)d_in[4];
  const float* q_weight = (const float*)d_in[5];
  const float* cq_weight = (const float*)d_in[6];
  const float* bias = (const float*)d_in[7];
  const float* wq1 = (const float*)d_in[8];
  const float* bq1 = (const float*)d_in[9];
  const float* wk1 = (const float*)d_in[10];
  const float* bk1 = (const float*)d_in[11];
  const float* gamma = (const float*)d_in[12];
  const float* beta = (const float*)d_in[13];
  const float* wq2 = (const float*)d_in[14];
  const float* bq2 = (const float*)d_in[15];
  const float* wk2 = (const float*)d_in[16];
  const float* bk2 = (const float*)d_in[17];
  float* out = (float*)d_out;

  // ---- workspace layout (floats). Early buffers alias qh2's region:
  // they are all dead before qh2 is first written (stage 16). Peak = 243.3 MB.
  float* base = (float*)d_ws;
  const size_t SZ_BCQ = (size_t)B_ * CL * QL;          // 262144
  const size_t SZ_BCH = (size_t)B_ * CL * H_;          // 3145728
  const size_t SZ_BQH = (size_t)B_ * QL * H_;          // 393216
  const size_t SZ_BCE = (size_t)B_ * CL * E2;          // 18874368
  const size_t SZ_BCC = (size_t)B_ * CL * CL;          // 2097152

  float* qh2 = base;
  float* ssb = base + SZ_BCE;
  float* ss1 = ssb + SZ_BCC;
  float* kh2 = ss1 + SZ_BCC;
  float* y   = kh2 + SZ_BCE;
  // early (aliased under qh2):
  float* e = base;
  float* s      = e; e += SZ_BCQ;
  float* s1m    = e; e += SZ_BCQ;
  float* s2m    = e; e += SZ_BCQ;
  float* scoatb = e; e += SZ_BCQ;
  float* scoat1 = e; e += SZ_BCQ;
  float* scoat2 = e; e += SZ_BCQ;
  float* s0buf  = e; e += (size_t)B_ * CL;
  float* s1buf  = e; e += (size_t)B_ * QL;
  float* qh1    = e; e += SZ_BCH;
  float* kh1    = e; e += SZ_BQH;
  float* a_     = e; e += SZ_BCH;
  float* U_     = e; e += SZ_BQH;
  float* bfull  = e; e += SZ_BCH;
  float* acoat  = e; e += SZ_BCH;
  float* bcoat  = e; e += SZ_BQH;
  float* scoat3 = e; e += SZ_BCH;

  // 1. s0, s1 row dots
  k_rowdot<<<B_ * CL / 4, 256, 0, stream>>>(c, c_weight, s0buf, H_);
  k_rowdot<<<B_ * QL / 4, 256, 0, stream>>>(q, q_weight, s1buf, H_);
  // 2. s
  k_s_assemble<<<dim3(CL / 32, B_), 256, 0, stream>>>(c, q, cq_weight, s0buf,
                                                      s1buf, bias, s);
  // 3-4. masked softmaxes
  k_rowsm64<<<B_ * CL / 4, 256, 0, stream>>>(s, q_mask, s1m);
  k_colsm<<<dim3(QL, B_), 256, 0, stream>>>(s, c_mask, s2m, QL);
  // 5-7. a, U = s2m^T@c, b = s1m@U
  k_gemm_bt<<<dim3(H_ / 64, CL / 32, B_), 256, 0, stream>>>(s1m, q, a_, CL, QL, H_, 0, 0);
  k_gemm_bt<<<dim3(H_ / 64, QL / 32, B_), 256, 0, stream>>>(s2m, c, U_, QL, CL, H_, 1, 0);
  k_gemm_bt<<<dim3(H_ / 64, CL / 32, B_), 256, 0, stream>>>(s1m, U_, bfull, CL, QL, H_, 0, 0);
  // 8. qh1, kh1
  k_gemm_nt<<<dim3(H_ / 64, B_ * CL / 128), 256, 0, stream>>>(c, wq1, bq1, qh1, H_, H_);
  k_gemm_nt<<<dim3(H_ / 64, B_ * QL / 128), 256, 0, stream>>>(q, wk1, bk1, kh1, H_, H_);
  // 9-11. scoat + its masked softmaxes
  k_mha1<<<B_ * CL, 256, 0, stream>>>(qh1, kh1, scoatb);
  k_rowsm64<<<B_ * CL / 4, 256, 0, stream>>>(scoatb, q_mask, scoat1);
  k_colsm<<<dim3(QL, B_), 256, 0, stream>>>(scoatb, c_mask, scoat2, QL);
  // 12-14. acoat, bcoat, scoat3
  k_gemm_bt<<<dim3(H_ / 64, CL / 32, B_), 256, 0, stream>>>(scoat1, q, acoat, CL, QL, H_, 0, 0);
  k_gemm_bt<<<dim3(H_ / 64, QL / 32, B_), 256, 0, stream>>>(scoat2, c, bcoat, QL, CL, H_, 1, 0);
  k_gemm_bt<<<dim3(H_ / 64, CL / 32, B_), 256, 0, stream>>>(scoat1, bcoat, scoat3, CL, QL, H_, 0, 0);
  // 15. x (-> d_out) + layernorm y
  k_xln<<<B_ * CL, 256, 0, stream>>>(c, a_, bfull, scoat3, acoat, gamma, beta, out, y);
  // 16. big NT GEMMs (early buffers dead; qh2 aliases them)
  k_gemm_nt<<<dim3(E2 / 64, B_ * CL / 128), 256, 0, stream>>>(y, wq2, bq2, qh2, E2, E2);
  k_gemm_nt<<<dim3(E2 / 64, B_ * CL / 128), 256, 0, stream>>>(y, wk2, bk2, kh2, E2, E2);
  // 17. fused 24-head probs mean
  k_ss<<<dim3(CL / 16, B_), 256, 0, stream>>>(qh2, kh2, ssb);
  // 18. masked col softmax over c
  k_colsm<<<dim3(CL, B_), 256, 0, stream>>>(ssb, c_mask, ss1, CL);
  // 19. patt = ss1 @ y + x (x already in d_out; addout=1)
  k_gemm_bt<<<dim3(E2 / 64, CL / 32, B_), 256, 0, stream>>>(ss1, y, out, CL, CL, E2, 0, 1);
}

// Round 2
// 2861.451 us; speedup vs baseline: 2.2704x; 2.2704x over previous
//
// QANet-style fused attention block, MI355X. R2: big E2xE2 GEMMs -> bf16 MFMA.
// Journal: R1 baseline 6497us, absmax 0.0156; k_gemm_nt(E2) 2x2790us = 86%.
// R2: qh2/kh2 via mfma_f32_16x16x32_bf16 (128x128xBK64 tile, global_load_lds
// w=16, 2-barrier loop, XCD swizzle). qh2/kh2/y_bf stored bf16 (score path is
// double-softmax-attenuated -> bf16-safe). x-path (stages 1-15) stays fp32.
// WS layout (bytes): [y f32 75.5M][ybf 37.7M][qh2b 37.7M][kh2b 37.7M][wbf 42.5M
// (later ssb/ss1)] = 231.2MB <= 243.3MB proven. Early bufs alias dead regions.
#include <hip/hip_runtime.h>

#define B_ 8
#define CL 512
#define QL 64
#define H_ 768
#define E2 4608
#define NH2 24
#define HD 192
#define NEGV -1e30f
#define SCALE 0.07216878364870323f  // 1/sqrt(192)

typedef __attribute__((ext_vector_type(8))) short bf16x8;
typedef __attribute__((ext_vector_type(4))) float f32x4;

__device__ __forceinline__ float wave_max(float v) {
#pragma unroll
  for (int m = 32; m >= 1; m >>= 1) v = fmaxf(v, __shfl_xor(v, m, 64));
  return v;
}
__device__ __forceinline__ float wave_sum(float v) {
#pragma unroll
  for (int m = 32; m >= 1; m >>= 1) v += __shfl_xor(v, m, 64);
  return v;
}
__device__ __forceinline__ unsigned short f2bf(float f) {
  union { float f; unsigned u; } a; a.f = f;
  unsigned u = a.u;
  unsigned r = u + 0x7fffu + ((u >> 16) & 1u);  // RNE
  return (unsigned short)(r >> 16);
}
__device__ __forceinline__ void cvt8(uint4 v, float* f) {
  f[0] = __uint_as_float(v.x << 16); f[1] = __uint_as_float(v.x & 0xffff0000u);
  f[2] = __uint_as_float(v.y << 16); f[3] = __uint_as_float(v.y & 0xffff0000u);
  f[4] = __uint_as_float(v.z << 16); f[5] = __uint_as_float(v.z & 0xffff0000u);
  f[6] = __uint_as_float(v.w << 16); f[7] = __uint_as_float(v.w & 0xffff0000u);
}
__device__ __forceinline__ void gload16(const void* g, void* l) {
  __builtin_amdgcn_global_load_lds(
      (const __attribute__((address_space(1))) unsigned int*)g,
      (__attribute__((address_space(3))) unsigned int*)l, 16, 0, 0);
}

// out[r] = dot(in[r, :K], w[:K]); one wave per row.
__global__ __launch_bounds__(256) void k_rowdot(const float* __restrict__ in,
                                                const float* __restrict__ w,
                                                float* __restrict__ out, int K) {
  int t = threadIdx.x, lane = t & 63, wv = t >> 6;
  int row = blockIdx.x * 4 + wv;
  const float* ip = in + (size_t)row * K;
  float s = 0.f;
  for (int j = lane; j < K; j += 64) s += ip[j] * w[j];
  s = wave_sum(s);
  if (lane == 0) out[row] = s;
}

// s[b,c,q] = s0[b,c] + s1[b,q] + sum_h c[b,c,h]*cqw[h]*q[b,q,h] + bias
__global__ __launch_bounds__(256) void k_s_assemble(
    const float* __restrict__ c, const float* __restrict__ q,
    const float* __restrict__ cqw, const float* __restrict__ s0,
    const float* __restrict__ s1, const float* __restrict__ bias,
    float* __restrict__ s) {
  int b = blockIdx.y, c0 = blockIdx.x * 32;
  int t = threadIdx.x, qq = t & 63, grp = t >> 6;
  __shared__ float qs[64][33];
  __shared__ float cs[32][33];
  float acc[8] = {};
  int qr = t >> 2, qc = (t & 3) * 8;
  for (int k0 = 0; k0 < H_; k0 += 32) {
    float qbuf[8], cbuf[8] = {};
    {
      const float4* qp = (const float4*)(q + (size_t)(b * QL + qr) * H_ + k0 + qc);
      float4 q0 = qp[0], q1 = qp[1];
      qbuf[0]=q0.x; qbuf[1]=q0.y; qbuf[2]=q0.z; qbuf[3]=q0.w;
      qbuf[4]=q1.x; qbuf[5]=q1.y; qbuf[6]=q1.z; qbuf[7]=q1.w;
    }
    if (t < 128) {
      int cr = t >> 2, cc = (t & 3) * 8;
      const float4* cp = (const float4*)(c + (size_t)(b * CL + c0 + cr) * H_ + k0 + cc);
      float4 c0v = cp[0], c1v = cp[1];
      float tmp[8] = {c0v.x,c0v.y,c0v.z,c0v.w,c1v.x,c1v.y,c1v.z,c1v.w};
#pragma unroll
      for (int j = 0; j < 8; ++j) cbuf[j] = tmp[j] * cqw[k0 + cc + j];
    }
    __syncthreads();
#pragma unroll
    for (int j = 0; j < 8; ++j) qs[qr][qc + j] = qbuf[j];
    if (t < 128) {
      int cr = t >> 2, cc = (t & 3) * 8;
#pragma unroll
      for (int j = 0; j < 8; ++j) cs[cr][cc + j] = cbuf[j];
    }
    __syncthreads();
#pragma unroll
    for (int kk = 0; kk < 32; ++kk) {
      float qv = qs[qq][kk];
#pragma unroll
      for (int i = 0; i < 8; ++i) acc[i] += cs[grp * 8 + i][kk] * qv;
    }
    __syncthreads();
  }
  float s1v = s1[b * QL + qq], b0 = bias[0];
#pragma unroll
  for (int i = 0; i < 8; ++i) {
    int cc = c0 + grp * 8 + i;
    s[(size_t)(b * CL + cc) * QL + qq] = acc[i] + s0[b * CL + cc] + s1v + b0;
  }
}

// masked softmax over last axis (len 64), mask = q_mask[b, q]; 1 wave/row.
__global__ __launch_bounds__(256) void k_rowsm64(const float* __restrict__ in,
                                                 const int* __restrict__ qmask,
                                                 float* __restrict__ out) {
  int t = threadIdx.x, lane = t & 63, wv = t >> 6;
  int row = blockIdx.x * 4 + wv;  // b*CL + c
  int b = row >> 9;
  float x = in[(size_t)row * QL + lane];
  float v = qmask[b * QL + lane] ? x : NEGV;
  float M = wave_max(v);
  float e = expf(v - M);
  float S = wave_sum(e);
  out[(size_t)row * QL + lane] = e / S;
}

// masked softmax over axis-1 (rows, len CL=512) for each (b, col); mask=c_mask[b,r].
__global__ __launch_bounds__(256) void k_colsm(const float* __restrict__ in,
                                               const int* __restrict__ cmask,
                                               float* __restrict__ out, int C) {
  int b = blockIdx.y, col = blockIdx.x, t = threadIdx.x;
  int lane = t & 63, wv = t >> 6;
  const float* ip = in + (size_t)b * CL * C + col;
  float* op = out + (size_t)b * CL * C + col;
  const int* mp = cmask + b * CL;
  float v0 = mp[t] ? ip[(size_t)t * C] : NEGV;
  float v1 = mp[t + 256] ? ip[(size_t)(t + 256) * C] : NEGV;
  __shared__ float red[4];
  float m = wave_max(fmaxf(v0, v1));
  if (lane == 0) red[wv] = m;
  __syncthreads();
  float M = fmaxf(fmaxf(red[0], red[1]), fmaxf(red[2], red[3]));
  __syncthreads();
  float e0 = expf(v0 - M), e1 = expf(v1 - M);
  float s = wave_sum(e0 + e1);
  if (lane == 0) red[wv] = s;
  __syncthreads();
  float S = red[0] + red[1] + red[2] + red[3];
  op[(size_t)t * C] = e0 / S;
  op[(size_t)(t + 256) * C] = e1 / S;
}

// Batched GEMM: out[b,m,n] = sum_k A[b,(ta? k*M+m : m*K+k)] * Bm[b,k*N+n]
// (+ out if addout). Tile 32m x 64n x 32k, 256 thr, 8 rows/thread.
__global__ __launch_bounds__(256) void k_gemm_bt(const float* __restrict__ A,
                                                 const float* __restrict__ Bm,
                                                 float* __restrict__ out, int M,
                                                 int K, int N, int ta, int addout) {
  int b = blockIdx.z;
  int n0 = blockIdx.x * 64, m0 = blockIdx.y * 32;
  const float* Ab = A + (size_t)b * M * K;
  const float* Bb = Bm + (size_t)b * K * N;
  float* Ob = out + (size_t)b * M * N;
  int t = threadIdx.x, lane = t & 63, mg = (t >> 6) * 8;
  __shared__ float As[32][36];
  __shared__ float Bs[32][64];
  float acc[8] = {};
  for (int k0 = 0; k0 < K; k0 += 32) {
    float4 av; float4 bv0, bv1;
    if (!ta) {
      int r = t >> 3, cc = (t & 7) * 4;
      av = *(const float4*)(Ab + (size_t)(m0 + r) * K + k0 + cc);
    } else {
      int kk = t >> 3, r4 = (t & 7) * 4;
      av = *(const float4*)(Ab + (size_t)(k0 + kk) * M + m0 + r4);
    }
    {
      int kk = t >> 3, n8 = (t & 7) * 8;
      const float4* bp = (const float4*)(Bb + (size_t)(k0 + kk) * N + n0 + n8);
      bv0 = bp[0]; bv1 = bp[1];
    }
    __syncthreads();
    if (!ta) {
      int r = t >> 3, cc = (t & 7) * 4;
      As[r][cc] = av.x; As[r][cc + 1] = av.y; As[r][cc + 2] = av.z; As[r][cc + 3] = av.w;
    } else {
      int kk = t >> 3, r4 = (t & 7) * 4;
      As[r4][kk] = av.x; As[r4 + 1][kk] = av.y; As[r4 + 2][kk] = av.z; As[r4 + 3][kk] = av.w;
    }
    {
      int kk = t >> 3, n8 = (t & 7) * 8;
      float tmp[8] = {bv0.x,bv0.y,bv0.z,bv0.w,bv1.x,bv1.y,bv1.z,bv1.w};
#pragma unroll
      for (int j = 0; j < 8; ++j) Bs[kk][n8 + j] = tmp[j];
    }
    __syncthreads();
#pragma unroll 4
    for (int kk = 0; kk < 32; ++kk) {
      float bv = Bs[kk][lane];
#pragma unroll
      for (int i = 0; i < 8; ++i) acc[i] += As[mg + i][kk] * bv;
    }
    __syncthreads();
  }
#pragma unroll
  for (int i = 0; i < 8; ++i) {
    size_t idx = (size_t)(m0 + mg + i) * N + n0 + lane;
    Ob[idx] = acc[i] + (addout ? Ob[idx] : 0.f);
  }
}

// fp32 NT weight GEMM (kept for the small H=768 qh1/kh1 projections).
__global__ __launch_bounds__(256) void k_gemm_nt(const float* __restrict__ A,
                                                 const float* __restrict__ W,
                                                 const float* __restrict__ bias,
                                                 float* __restrict__ out, int K,
                                                 int N) {
  int n0 = blockIdx.x * 64, m0 = blockIdx.y * 128;
  int t = threadIdx.x;
  __shared__ float At[32][128];
  __shared__ float Wt[32][64];
  float acc[8][4] = {};
  int ar = t >> 1, ac = (t & 1) * 16;
  int wr = t >> 2, wc = (t & 3) * 8;
  const float* Ap = A + (size_t)(m0 + ar) * K + ac;
  const float* Wp = W + (size_t)(n0 + wr) * K + wc;
  int mg = (t >> 4) * 8, ng = (t & 15) * 4;
  for (int k0 = 0; k0 < K; k0 += 32) {
    float4 a4[4], w4[2];
    {
      const float4* ap = (const float4*)(Ap + k0);
#pragma unroll
      for (int j = 0; j < 4; ++j) a4[j] = ap[j];
      const float4* wp = (const float4*)(Wp + k0);
      w4[0] = wp[0]; w4[1] = wp[1];
    }
    __syncthreads();
    {
      float ta[16] = {a4[0].x,a4[0].y,a4[0].z,a4[0].w, a4[1].x,a4[1].y,a4[1].z,a4[1].w,
                      a4[2].x,a4[2].y,a4[2].z,a4[2].w, a4[3].x,a4[3].y,a4[3].z,a4[3].w};
#pragma unroll
      for (int j = 0; j < 16; ++j) At[ac + j][ar] = ta[j];
      float tw[8] = {w4[0].x,w4[0].y,w4[0].z,w4[0].w, w4[1].x,w4[1].y,w4[1].z,w4[1].w};
#pragma unroll
      for (int j = 0; j < 8; ++j) Wt[wc + j][wr] = tw[j];
    }
    __syncthreads();
#pragma unroll
    for (int kk = 0; kk < 32; ++kk) {
      float4 wv = *(const float4*)&Wt[kk][ng];
      float4 a0 = *(const float4*)&At[kk][mg];
      float4 a1 = *(const float4*)&At[kk][mg + 4];
      float am[8] = {a0.x,a0.y,a0.z,a0.w,a1.x,a1.y,a1.z,a1.w};
      float wn[4] = {wv.x,wv.y,wv.z,wv.w};
#pragma unroll
      for (int i = 0; i < 8; ++i)
#pragma unroll
        for (int j = 0; j < 4; ++j) acc[i][j] += am[i] * wn[j];
    }
    __syncthreads();
  }
  float bv[4];
#pragma unroll
  for (int j = 0; j < 4; ++j) bv[j] = bias[n0 + ng + j];
#pragma unroll
  for (int i = 0; i < 8; ++i) {
    float4 o;
    o.x = acc[i][0] + bv[0]; o.y = acc[i][1] + bv[1];
    o.z = acc[i][2] + bv[2]; o.w = acc[i][3] + bv[3];
    *(float4*)(out + (size_t)(m0 + mg + i) * N + n0 + ng) = o;
  }
}

// fp32 -> bf16 cast, 8 elems/thread, exact grid.
__global__ __launch_bounds__(256) void k_cast(const float* __restrict__ in,
                                              unsigned short* __restrict__ ob) {
  size_t i = ((size_t)blockIdx.x * 256 + threadIdx.x) * 8;
  const float4* p = (const float4*)(in + i);
  float4 v0 = p[0], v1 = p[1];
  uint4 o;
  o.x = (unsigned)f2bf(v0.x) | ((unsigned)f2bf(v0.y) << 16);
  o.y = (unsigned)f2bf(v0.z) | ((unsigned)f2bf(v0.w) << 16);
  o.z = (unsigned)f2bf(v1.x) | ((unsigned)f2bf(v1.y) << 16);
  o.w = (unsigned)f2bf(v1.z) | ((unsigned)f2bf(v1.w) << 16);
  *(uint4*)(ob + i) = o;
}

// bf16 MFMA NT GEMM: out_bf[m,n] = bf16( sum_k A[m,k]*W[n,k] + bias[n] ).
// 128x128 tile, BK=64, 4 waves in 2x2, 4x4 16x16x32 frags/wave (m97 structure).
// Staging: global_load_lds dwordx4 (16B/lane), linear LDS [128][64] bf16.
__global__ __launch_bounds__(256) void k_gemm_bf16(
    const unsigned short* __restrict__ A, const unsigned short* __restrict__ W,
    const float* __restrict__ bias, unsigned short* __restrict__ out, int K,
    int N) {
  __shared__ __align__(16) unsigned short As[128 * 64];
  __shared__ __align__(16) unsigned short Ws[128 * 64];
  int t = threadIdx.x, lane = t & 63, wv = t >> 6;
  // XCD-aware bijective swizzle (nwg = 36*32 = 1152, %8==0).
  int nwg = gridDim.x * gridDim.y;
  int lin = blockIdx.y * gridDim.x + blockIdx.x;
  int swz = (lin & 7) * (nwg >> 3) + (lin >> 3);
  int n0 = (swz % gridDim.x) * 128, m0 = (swz / gridDim.x) * 128;
  int wr = wv >> 1, wc = wv & 1;
  f32x4 acc[4][4];
#pragma unroll
  for (int i = 0; i < 4; ++i)
#pragma unroll
    for (int j = 0; j < 4; ++j) acc[i][j] = (f32x4){0.f, 0.f, 0.f, 0.f};
  int scol = (lane & 7) * 8;  // staging k-col (8 bf16 = 16B)
  int arow = wr * 64 + (lane & 15), brow = wc * 64 + (lane & 15);
  int ko_ = (lane >> 4) * 8;
  for (int k0 = 0; k0 < K; k0 += 64) {
#pragma unroll
    for (int i = 0; i < 4; ++i) {
      int chunk = wv * 4 + i;
      int row = chunk * 8 + (lane >> 3);
      gload16(A + (size_t)(m0 + row) * K + k0 + scol, &As[chunk * 512]);
      gload16(W + (size_t)(n0 + row) * K + k0 + scol, &Ws[chunk * 512]);
    }
    __syncthreads();  // compiler drains vmcnt(0) here -> LDS ready
#pragma unroll
    for (int ks = 0; ks < 2; ++ks) {
      bf16x8 af[4], bg[4];
#pragma unroll
      for (int mi = 0; mi < 4; ++mi)
        af[mi] = *(const bf16x8*)&As[(arow + mi * 16) * 64 + ks * 32 + ko_];
#pragma unroll
      for (int ni = 0; ni < 4; ++ni)
        bg[ni] = *(const bf16x8*)&Ws[(brow + ni * 16) * 64 + ks * 32 + ko_];
#pragma unroll
      for (int mi = 0; mi < 4; ++mi)
#pragma unroll
        for (int ni = 0; ni < 4; ++ni)
          acc[mi][ni] = __builtin_amdgcn_mfma_f32_16x16x32_bf16(
              af[mi], bg[ni], acc[mi][ni], 0, 0, 0);
    }
    __syncthreads();  // reads done before next stage overwrites
  }
#pragma unroll
  for (int mi = 0; mi < 4; ++mi)
#pragma unroll
    for (int ni = 0; ni < 4; ++ni) {
      int row = m0 + wr * 64 + mi * 16 + (lane >> 4) * 4;
      int col = n0 + wc * 64 + ni * 16 + (lane & 15);
      float bv = bias[col];
#pragma unroll
      for (int j = 0; j < 4; ++j)
        out[(size_t)(row + j) * N + col] = f2bf(acc[mi][ni][j] + bv);
    }
}

// MHA1 probs: scoat[b,c,q] = mean_h softmax_q(qh1[b,c,h]·kh1[b,q,h]/sqrt(192)).
__global__ __launch_bounds__(256) void k_mha1(const float* __restrict__ qh,
                                              const float* __restrict__ kh,
                                              float* __restrict__ scoat) {
  int blk = blockIdx.x;  // b*CL + c
  int b = blk >> 9;
  int t = threadIdx.x, lane = t & 63, h = t >> 6;
  __shared__ float qrow[H_];
  __shared__ float probs[4][64];
#pragma unroll
  for (int j = 0; j < 3; ++j) qrow[t + 256 * j] = qh[(size_t)blk * H_ + t + 256 * j];
  __syncthreads();
  const float* kp = kh + (size_t)(b * QL + lane) * H_ + h * HD;
  const float* qp = &qrow[h * HD];
  float sc = 0.f;
#pragma unroll 4
  for (int k = 0; k < HD; ++k) sc += qp[k] * kp[k];
  sc *= SCALE;
  float M = wave_max(sc);
  float e = expf(sc - M);
  float S = wave_sum(e);
  probs[h][lane] = e / S;
  __syncthreads();
  if (t < 64)
    scoat[(size_t)blk * QL + t] =
        0.25f * (probs[0][t] + probs[1][t] + probs[2][t] + probs[3][t]);
}

// Fused 24-head scores + softmax + head-mean: ss[b,c,d]. bf16 qh2/kh2 inputs.
__global__ __launch_bounds__(256) void k_ss(const unsigned short* __restrict__ qh,
                                            const unsigned short* __restrict__ kh,
                                            float* __restrict__ ss) {
  int b = blockIdx.y, c0 = blockIdx.x * 16;
  int t = threadIdx.x, lane = t & 63, wv = t >> 6;
  __shared__ float qt[16 * 192];
  __shared__ float kt[64 * 193];
  float* red = kt;  // alias: [4][16][64], protected by barriers
  float score[4][8];
  float macc[4][8];
#pragma unroll
  for (int i = 0; i < 4; ++i)
#pragma unroll
    for (int j = 0; j < 8; ++j) macc[i][j] = 0.f;
  for (int h = 0; h < NH2; ++h) {
    {  // stage q-tile: 16 rows x 192 bf16 = 384 chunks of 8
      int r = t / 24, j = t % 24;
      uint4 v = *(const uint4*)(qh + (size_t)(b * CL + c0 + r) * E2 + h * HD + j * 8);
      float f[8]; cvt8(v, f);
#pragma unroll
      for (int e = 0; e < 8; ++e) qt[r * 192 + j * 8 + e] = f[e];
      if (t < 128) {
        int c2 = 256 + t;
        int r2 = c2 / 24, j2 = c2 % 24;
        uint4 v2 = *(const uint4*)(qh + (size_t)(b * CL + c0 + r2) * E2 + h * HD + j2 * 8);
        float g[8]; cvt8(v2, g);
#pragma unroll
        for (int e = 0; e < 8; ++e) qt[r2 * 192 + j2 * 8 + e] = g[e];
      }
    }
    for (int d0 = 0; d0 < CL; d0 += 64) {
      {  // stage k-tile: 64 rows x 192 bf16 = 1536 chunks of 8, stride 193
#pragma unroll
        for (int i = 0; i < 6; ++i) {
          int cc = t + i * 256;
          int r = cc / 24, j = cc % 24;
          uint4 v = *(const uint4*)(kh + (size_t)(b * CL + d0 + r) * E2 + h * HD + j * 8);
          float f[8]; cvt8(v, f);
#pragma unroll
          for (int e = 0; e < 8; ++e) kt[r * 193 + j * 8 + e] = f[e];
        }
      }
      __syncthreads();
      float pacc[16];
#pragma unroll
      for (int r = 0; r < 16; ++r) pacc[r] = 0.f;
      const int kb = wv * 48;
      for (int kk = 0; kk < 48; kk += 4) {
        float kv0 = kt[lane * 193 + kb + kk];
        float kv1 = kt[lane * 193 + kb + kk + 1];
        float kv2 = kt[lane * 193 + kb + kk + 2];
        float kv3 = kt[lane * 193 + kb + kk + 3];
#pragma unroll
        for (int r = 0; r < 16; ++r) {
          const float* qp = &qt[r * 192 + kb + kk];
          pacc[r] += qp[0] * kv0 + qp[1] * kv1 + qp[2] * kv2 + qp[3] * kv3;
        }
      }
      __syncthreads();  // kt reads done -> red may overwrite
#pragma unroll
      for (int r = 0; r < 16; ++r) red[(wv * 16 + r) * 64 + lane] = pacc[r];
      __syncthreads();
      int ch = d0 >> 6;
#pragma unroll
      for (int i = 0; i < 4; ++i) {
        int r = wv + 4 * i;
        score[i][ch] = red[r * 64 + lane] + red[(16 + r) * 64 + lane] +
                       red[(32 + r) * 64 + lane] + red[(48 + r) * 64 + lane];
      }
      __syncthreads();  // red reads done before next kt stage
    }
#pragma unroll
    for (int i = 0; i < 4; ++i) {
      float m = -1e30f;
#pragma unroll
      for (int j = 0; j < 8; ++j) m = fmaxf(m, score[i][j]);
      m = wave_max(m);
      float e[8], sl = 0.f;
#pragma unroll
      for (int j = 0; j < 8; ++j) {
        e[j] = expf((score[i][j] - m) * SCALE);
        sl += e[j];
      }
      float S = wave_sum(sl);
      float inv = 1.f / (S * 24.f);
#pragma unroll
      for (int j = 0; j < 8; ++j) macc[i][j] += e[j] * inv;
    }
  }
#pragma unroll
  for (int i = 0; i < 4; ++i) {
    int r = wv + 4 * i;
#pragma unroll
    for (int j = 0; j < 8; ++j)
      ss[(size_t)(b * CL + c0 + r) * CL + j * 64 + lane] = macc[i][j];
  }
}

// concat x -> d_out; layernorm -> y (f32) + ybf (bf16).
__global__ __launch_bounds__(256) void k_xln(
    const float* __restrict__ c, const float* __restrict__ a,
    const float* __restrict__ bf, const float* __restrict__ s3,
    const float* __restrict__ ac, const float* __restrict__ gamma,
    const float* __restrict__ beta, float* __restrict__ xout,
    float* __restrict__ y, unsigned short* __restrict__ ybf) {
  int row = blockIdx.x, t = threadIdx.x, lane = t & 63, wv = t >> 6;
  size_t base = (size_t)row * H_;
  float xs[6][3];
  float sum = 0.f, sq = 0.f;
#pragma unroll
  for (int kk = 0; kk < 3; ++kk) {
    int j = t + kk * 256;
    float cv = c[base + j], av = a[base + j], bv = bf[base + j];
    float sv = s3[base + j], av2 = ac[base + j];
    xs[0][kk] = cv; xs[1][kk] = av; xs[2][kk] = cv * av;
    xs[3][kk] = cv * bv; xs[4][kk] = sv; xs[5][kk] = av2;
  }
#pragma unroll
  for (int s = 0; s < 6; ++s)
#pragma unroll
    for (int kk = 0; kk < 3; ++kk) {
      sum += xs[s][kk];
      sq += xs[s][kk] * xs[s][kk];
    }
  sum = wave_sum(sum);
  sq = wave_sum(sq);
  __shared__ float red[4][2];
  if (lane == 0) { red[wv][0] = sum; red[wv][1] = sq; }
  __syncthreads();
  float TS = red[0][0] + red[1][0] + red[2][0] + red[3][0];
  float TQ = red[0][1] + red[1][1] + red[2][1] + red[3][1];
  float mu = TS * (1.f / (float)E2);
  float var = TQ * (1.f / (float)E2) - mu * mu;
  float rstd = rsqrtf(var + 1e-5f);
  size_t obase = (size_t)row * E2;
#pragma unroll
  for (int s = 0; s < 6; ++s)
#pragma unroll
    for (int kk = 0; kk < 3; ++kk) {
      int col = s * H_ + t + kk * 256;
      float xv = xs[s][kk];
      float yv = (xv - mu) * rstd * gamma[col] + beta[col];
      xout[obase + col] = xv;
      y[obase + col] = yv;
      ybf[obase + col] = f2bf(yv);
    }
}

extern "C" void kernel_launch(void* const* d_in, const int* in_sizes, int n_in,
                              void* d_out, int out_size, void* d_ws,
                              size_t ws_size, hipStream_t stream) {
  const float* c = (const float*)d_in[0];
  const float* q = (const float*)d_in[1];
  const int* c_mask = (const int*)d_in[2];
  const int* q_mask = (const int*)d_in[3];
  const float* c_weight = (const float*)d_in[4];
  const float* q_weight = (const float*)d_in[5];
  const float* cq_weight = (const float*)d_in[6];
  const float* bias = (const float*)d_in[7];
  const float* wq1 = (const float*)d_in[8];
  const float* bq1 = (const float*)d_in[9];
  const float* wk1 = (const float*)d_in[10];
  const float* bk1 = (const float*)d_in[11];
  const float* gamma = (const float*)d_in[12];
  const float* beta = (const float*)d_in[13];
  const float* wq2 = (const float*)d_in[14];
  const float* bq2 = (const float*)d_in[15];
  const float* wk2 = (const float*)d_in[16];
  const float* bk2 = (const float*)d_in[17];
  float* out = (float*)d_out;

  // ---- workspace layout (bytes); total 231,211,008 <= 243.3MB proven.
  char* wsb = (char*)d_ws;
  float* y = (float*)wsb;                                        // 75,497,472
  unsigned short* ybf = (unsigned short*)(wsb + 75497472);       // 37,748,736
  unsigned short* qh2b = (unsigned short*)(wsb + 113246208);     // 37,748,736
  unsigned short* kh2b = (unsigned short*)(wsb + 150994944);     // 37,748,736
  unsigned short* wbf = (unsigned short*)(wsb + 188743680);      // 42,467,328
  float* ssb = (float*)(wsb + 188743680);   // alias wbf (dead after GEMM2)
  float* ss1 = ssb + 2097152;
  // early dead-before-LN buffers live inside [y] region (y written stage 15):
  float* e = (float*)wsb;
  float* s      = e; e += 262144;
  float* s1m    = e; e += 262144;
  float* s2m    = e; e += 262144;
  float* scoatb = e; e += 262144;
  float* scoat1 = e; e += 262144;
  float* scoat2 = e; e += 262144;
  float* s0buf  = e; e += 4096;
  float* s1buf  = e; e += 512;
  float* qh1    = e; e += 3145728;
  float* kh1    = e; e += 393216;
  float* U_     = e; e += 393216;
  float* bcoat  = e; e += 393216;
  // k_xln inputs live in [qh2b..] region (overwritten only at stage 16+):
  float* a_     = (float*)(wsb + 113246208);
  float* bfull  = a_ + 3145728;
  float* acoat  = bfull + 3145728;
  float* scoat3 = acoat + 3145728;

  // 1. s0, s1 row dots
  k_rowdot<<<B_ * CL / 4, 256, 0, stream>>>(c, c_weight, s0buf, H_);
  k_rowdot<<<B_ * QL / 4, 256, 0, stream>>>(q, q_weight, s1buf, H_);
  // 2. s
  k_s_assemble<<<dim3(CL / 32, B_), 256, 0, stream>>>(c, q, cq_weight, s0buf,
                                                      s1buf, bias, s);
  // 3-4. masked softmaxes
  k_rowsm64<<<B_ * CL / 4, 256, 0, stream>>>(s, q_mask, s1m);
  k_colsm<<<dim3(QL, B_), 256, 0, stream>>>(s, c_mask, s2m, QL);
  // 5-7. a, U = s2m^T@c, b = s1m@U
  k_gemm_bt<<<dim3(H_ / 64, CL / 32, B_), 256, 0, stream>>>(s1m, q, a_, CL, QL, H_, 0, 0);
  k_gemm_bt<<<dim3(H_ / 64, QL / 32, B_), 256, 0, stream>>>(s2m, c, U_, QL, CL, H_, 1, 0);
  k_gemm_bt<<<dim3(H_ / 64, CL / 32, B_), 256, 0, stream>>>(s1m, U_, bfull, CL, QL, H_, 0, 0);
  // 8. qh1, kh1 (small fp32 NT GEMMs)
  k_gemm_nt<<<dim3(H_ / 64, B_ * CL / 128), 256, 0, stream>>>(c, wq1, bq1, qh1, H_, H_);
  k_gemm_nt<<<dim3(H_ / 64, B_ * QL / 128), 256, 0, stream>>>(q, wk1, bk1, kh1, H_, H_);
  // 9-11. scoat + its masked softmaxes
  k_mha1<<<B_ * CL, 256, 0, stream>>>(qh1, kh1, scoatb);
  k_rowsm64<<<B_ * CL / 4, 256, 0, stream>>>(scoatb, q_mask, scoat1);
  k_colsm<<<dim3(QL, B_), 256, 0, stream>>>(scoatb, c_mask, scoat2, QL);
  // 12-14. acoat, bcoat, scoat3
  k_gemm_bt<<<dim3(H_ / 64, CL / 32, B_), 256, 0, stream>>>(scoat1, q, acoat, CL, QL, H_, 0, 0);
  k_gemm_bt<<<dim3(H_ / 64, QL / 32, B_), 256, 0, stream>>>(scoat2, c, bcoat, QL, CL, H_, 1, 0);
  k_gemm_bt<<<dim3(H_ / 64, CL / 32, B_), 256, 0, stream>>>(scoat1, bcoat, scoat3, CL, QL, H_, 0, 0);
  // 15. x (-> d_out) + layernorm y (f32 + bf16)
  k_xln<<<B_ * CL, 256, 0, stream>>>(c, a_, bfull, scoat3, acoat, gamma, beta,
                                     out, y, ybf);
  // 16. casts + big bf16 MFMA GEMMs
  k_cast<<<E2 * E2 / 2048, 256, 0, stream>>>(wq2, wbf);
  k_gemm_bf16<<<dim3(E2 / 128, B_ * CL / 128), 256, 0, stream>>>(ybf, wbf, bq2,
                                                                 qh2b, E2, E2);
  k_cast<<<E2 * E2 / 2048, 256, 0, stream>>>(wk2, wbf);
  k_gemm_bf16<<<dim3(E2 / 128, B_ * CL / 128), 256, 0, stream>>>(ybf, wbf, bk2,
                                                                 kh2b, E2, E2);
  // 17. fused 24-head probs mean (bf16 inputs)
  k_ss<<<dim3(CL / 16, B_), 256, 0, stream>>>(qh2b, kh2b, ssb);
  // 18. masked col softmax over c
  k_colsm<<<dim3(CL, B_), 256, 0, stream>>>(ssb, c_mask, ss1, CL);
  // 19. patt = ss1 @ y + x (x already in d_out; addout=1)
  k_gemm_bt<<<dim3(E2 / 64, CL / 32, B_), 256, 0, stream>>>(ss1, y, out, CL, CL, E2, 0, 1);
}

// Round 3
// 1649.790 us; speedup vs baseline: 3.9379x; 1.7344x over previous
//
// QANet-style fused attention block, MI355X. R3.
// Journal: R1 fp32 baseline 6497us; R2 bf16-MFMA big GEMMs 2861us (absmax
// 0.0156). R2 top: k_ss 1053us (MfmaUtil 0, VALU 38%, LDS-conflict 8.2e7).
// R3: (1) k_ss -> k_ssm: 24-head scores via mfma 16x16x32 bf16, swizzled
// global_load_lds staging, dbuf K-halves, in-reg softmax+mean, head-split x2.
// (2) stage19 -> k_gemm_nn bf16 MFMA (ss1 bf16 via k_colsm2bf, y as ybf only).
// (3) k_gemm_bf16 gets XOR bank-conflict swizzle (lane-XOR source + read).
// WS: [ybf 37.7M][qh2b 37.7M][kh2b 37.7M][wbf 42.5M][p0 8.4M][p1 8.4M]
// [ss1b 4.2M] = 176.7MB; early fp32 bufs (73.9MB) alias qh2b+kh2b (dead
// until stage 16). All proven <= 243.3MB.
#include <hip/hip_runtime.h>

#define B_ 8
#define CL 512
#define QL 64
#define H_ 768
#define E2 4608
#define NH2 24
#define HD 192
#define NEGV -1e30f
#define SCALE 0.07216878364870323f  // 1/sqrt(192)

typedef __attribute__((ext_vector_type(8))) short bf16x8;
typedef __attribute__((ext_vector_type(4))) float f32x4;

__device__ __forceinline__ float wave_max(float v) {
#pragma unroll
  for (int m = 32; m >= 1; m >>= 1) v = fmaxf(v, __shfl_xor(v, m, 64));
  return v;
}
__device__ __forceinline__ float wave_sum(float v) {
#pragma unroll
  for (int m = 32; m >= 1; m >>= 1) v += __shfl_xor(v, m, 64);
  return v;
}
__device__ __forceinline__ unsigned short f2bf(float f) {
  union { float f; unsigned u; } a; a.f = f;
  unsigned u = a.u;
  unsigned r = u + 0x7fffu + ((u >> 16) & 1u);  // RNE
  return (unsigned short)(r >> 16);
}
__device__ __forceinline__ void gload16(const void* g, void* l) {
  __builtin_amdgcn_global_load_lds(
      (const __attribute__((address_space(1))) unsigned int*)g,
      (__attribute__((address_space(3))) unsigned int*)l, 16, 0, 0);
}

// out[r] = dot(in[r, :K], w[:K]); one wave per row.
__global__ __launch_bounds__(256) void k_rowdot(const float* __restrict__ in,
                                                const float* __restrict__ w,
                                                float* __restrict__ out, int K) {
  int t = threadIdx.x, lane = t & 63, wv = t >> 6;
  int row = blockIdx.x * 4 + wv;
  const float* ip = in + (size_t)row * K;
  float s = 0.f;
  for (int j = lane; j < K; j += 64) s += ip[j] * w[j];
  s = wave_sum(s);
  if (lane == 0) out[row] = s;
}

// s[b,c,q] = s0[b,c] + s1[b,q] + sum_h c[b,c,h]*cqw[h]*q[b,q,h] + bias
__global__ __launch_bounds__(256) void k_s_assemble(
    const float* __restrict__ c, const float* __restrict__ q,
    const float* __restrict__ cqw, const float* __restrict__ s0,
    const float* __restrict__ s1, const float* __restrict__ bias,
    float* __restrict__ s) {
  int b = blockIdx.y, c0 = blockIdx.x * 32;
  int t = threadIdx.x, qq = t & 63, grp = t >> 6;
  __shared__ float qs[64][33];
  __shared__ float cs[32][33];
  float acc[8] = {};
  int qr = t >> 2, qc = (t & 3) * 8;
  for (int k0 = 0; k0 < H_; k0 += 32) {
    float qbuf[8], cbuf[8] = {};
    {
      const float4* qp = (const float4*)(q + (size_t)(b * QL + qr) * H_ + k0 + qc);
      float4 q0 = qp[0], q1 = qp[1];
      qbuf[0]=q0.x; qbuf[1]=q0.y; qbuf[2]=q0.z; qbuf[3]=q0.w;
      qbuf[4]=q1.x; qbuf[5]=q1.y; qbuf[6]=q1.z; qbuf[7]=q1.w;
    }
    if (t < 128) {
      int cr = t >> 2, cc = (t & 3) * 8;
      const float4* cp = (const float4*)(c + (size_t)(b * CL + c0 + cr) * H_ + k0 + cc);
      float4 c0v = cp[0], c1v = cp[1];
      float tmp[8] = {c0v.x,c0v.y,c0v.z,c0v.w,c1v.x,c1v.y,c1v.z,c1v.w};
#pragma unroll
      for (int j = 0; j < 8; ++j) cbuf[j] = tmp[j] * cqw[k0 + cc + j];
    }
    __syncthreads();
#pragma unroll
    for (int j = 0; j < 8; ++j) qs[qr][qc + j] = qbuf[j];
    if (t < 128) {
      int cr = t >> 2, cc = (t & 3) * 8;
#pragma unroll
      for (int j = 0; j < 8; ++j) cs[cr][cc + j] = cbuf[j];
    }
    __syncthreads();
#pragma unroll
    for (int kk = 0; kk < 32; ++kk) {
      float qv = qs[qq][kk];
#pragma unroll
      for (int i = 0; i < 8; ++i) acc[i] += cs[grp * 8 + i][kk] * qv;
    }
    __syncthreads();
  }
  float s1v = s1[b * QL + qq], b0 = bias[0];
#pragma unroll
  for (int i = 0; i < 8; ++i) {
    int cc = c0 + grp * 8 + i;
    s[(size_t)(b * CL + cc) * QL + qq] = acc[i] + s0[b * CL + cc] + s1v + b0;
  }
}

// masked softmax over last axis (len 64), mask = q_mask[b, q]; 1 wave/row.
__global__ __launch_bounds__(256) void k_rowsm64(const float* __restrict__ in,
                                                 const int* __restrict__ qmask,
                                                 float* __restrict__ out) {
  int t = threadIdx.x, lane = t & 63, wv = t >> 6;
  int row = blockIdx.x * 4 + wv;  // b*CL + c
  int b = row >> 9;
  float x = in[(size_t)row * QL + lane];
  float v = qmask[b * QL + lane] ? x : NEGV;
  float M = wave_max(v);
  float e = expf(v - M);
  float S = wave_sum(e);
  out[(size_t)row * QL + lane] = e / S;
}

// masked softmax over axis-1 (rows, len CL) for each (b, col); C=QL here.
__global__ __launch_bounds__(256) void k_colsm(const float* __restrict__ in,
                                               const int* __restrict__ cmask,
                                               float* __restrict__ out, int C) {
  int b = blockIdx.y, col = blockIdx.x, t = threadIdx.x;
  int lane = t & 63, wv = t >> 6;
  const float* ip = in + (size_t)b * CL * C + col;
  float* op = out + (size_t)b * CL * C + col;
  const int* mp = cmask + b * CL;
  float v0 = mp[t] ? ip[(size_t)t * C] : NEGV;
  float v1 = mp[t + 256] ? ip[(size_t)(t + 256) * C] : NEGV;
  __shared__ float red[4];
  float m = wave_max(fmaxf(v0, v1));
  if (lane == 0) red[wv] = m;
  __syncthreads();
  float M = fmaxf(fmaxf(red[0], red[1]), fmaxf(red[2], red[3]));
  __syncthreads();
  float e0 = expf(v0 - M), e1 = expf(v1 - M);
  float s = wave_sum(e0 + e1);
  if (lane == 0) red[wv] = s;
  __syncthreads();
  float S = red[0] + red[1] + red[2] + red[3];
  op[(size_t)t * C] = e0 / S;
  op[(size_t)(t + 256) * C] = e1 / S;
}

// Batched fp32 GEMM for the small QL-K products (stages 5-7, 12-14).
__global__ __launch_bounds__(256) void k_gemm_bt(const float* __restrict__ A,
                                                 const float* __restrict__ Bm,
                                                 float* __restrict__ out, int M,
                                                 int K, int N, int ta, int addout) {
  int b = blockIdx.z;
  int n0 = blockIdx.x * 64, m0 = blockIdx.y * 32;
  const float* Ab = A + (size_t)b * M * K;
  const float* Bb = Bm + (size_t)b * K * N;
  float* Ob = out + (size_t)b * M * N;
  int t = threadIdx.x, lane = t & 63, mg = (t >> 6) * 8;
  __shared__ float As[32][36];
  __shared__ float Bs[32][64];
  float acc[8] = {};
  for (int k0 = 0; k0 < K; k0 += 32) {
    float4 av; float4 bv0, bv1;
    if (!ta) {
      int r = t >> 3, cc = (t & 7) * 4;
      av = *(const float4*)(Ab + (size_t)(m0 + r) * K + k0 + cc);
    } else {
      int kk = t >> 3, r4 = (t & 7) * 4;
      av = *(const float4*)(Ab + (size_t)(k0 + kk) * M + m0 + r4);
    }
    {
      int kk = t >> 3, n8 = (t & 7) * 8;
      const float4* bp = (const float4*)(Bb + (size_t)(k0 + kk) * N + n0 + n8);
      bv0 = bp[0]; bv1 = bp[1];
    }
    __syncthreads();
    if (!ta) {
      int r = t >> 3, cc = (t & 7) * 4;
      As[r][cc] = av.x; As[r][cc + 1] = av.y; As[r][cc + 2] = av.z; As[r][cc + 3] = av.w;
    } else {
      int kk = t >> 3, r4 = (t & 7) * 4;
      As[r4][kk] = av.x; As[r4 + 1][kk] = av.y; As[r4 + 2][kk] = av.z; As[r4 + 3][kk] = av.w;
    }
    {
      int kk = t >> 3, n8 = (t & 7) * 8;
      float tmp[8] = {bv0.x,bv0.y,bv0.z,bv0.w,bv1.x,bv1.y,bv1.z,bv1.w};
#pragma unroll
      for (int j = 0; j < 8; ++j) Bs[kk][n8 + j] = tmp[j];
    }
    __syncthreads();
#pragma unroll 4
    for (int kk = 0; kk < 32; ++kk) {
      float bv = Bs[kk][lane];
#pragma unroll
      for (int i = 0; i < 8; ++i) acc[i] += As[mg + i][kk] * bv;
    }
    __syncthreads();
  }
#pragma unroll
  for (int i = 0; i < 8; ++i) {
    size_t idx = (size_t)(m0 + mg + i) * N + n0 + lane;
    Ob[idx] = acc[i] + (addout ? Ob[idx] : 0.f);
  }
}

// fp32 NT weight GEMM (small H=768 qh1/kh1 projections).
__global__ __launch_bounds__(256) void k_gemm_nt(const float* __restrict__ A,
                                                 const float* __restrict__ W,
                                                 const float* __restrict__ bias,
                                                 float* __restrict__ out, int K,
                                                 int N) {
  int n0 = blockIdx.x * 64, m0 = blockIdx.y * 128;
  int t = threadIdx.x;
  __shared__ float At[32][128];
  __shared__ float Wt[32][64];
  float acc[8][4] = {};
  int ar = t >> 1, ac = (t & 1) * 16;
  int wr = t >> 2, wc = (t & 3) * 8;
  const float* Ap = A + (size_t)(m0 + ar) * K + ac;
  const float* Wp = W + (size_t)(n0 + wr) * K + wc;
  int mg = (t >> 4) * 8, ng = (t & 15) * 4;
  for (int k0 = 0; k0 < K; k0 += 32) {
    float4 a4[4], w4[2];
    {
      const float4* ap = (const float4*)(Ap + k0);
#pragma unroll
      for (int j = 0; j < 4; ++j) a4[j] = ap[j];
      const float4* wp = (const float4*)(Wp + k0);
      w4[0] = wp[0]; w4[1] = wp[1];
    }
    __syncthreads();
    {
      float ta[16] = {a4[0].x,a4[0].y,a4[0].z,a4[0].w, a4[1].x,a4[1].y,a4[1].z,a4[1].w,
                      a4[2].x,a4[2].y,a4[2].z,a4[2].w, a4[3].x,a4[3].y,a4[3].z,a4[3].w};
#pragma unroll
      for (int j = 0; j < 16; ++j) At[ac + j][ar] = ta[j];
      float tw[8] = {w4[0].x,w4[0].y,w4[0].z,w4[0].w, w4[1].x,w4[1].y,w4[1].z,w4[1].w};
#pragma unroll
      for (int j = 0; j < 8; ++j) Wt[wc + j][wr] = tw[j];
    }
    __syncthreads();
#pragma unroll
    for (int kk = 0; kk < 32; ++kk) {
      float4 wv = *(const float4*)&Wt[kk][ng];
      float4 a0 = *(const float4*)&At[kk][mg];
      float4 a1 = *(const float4*)&At[kk][mg + 4];
      float am[8] = {a0.x,a0.y,a0.z,a0.w,a1.x,a1.y,a1.z,a1.w};
      float wn[4] = {wv.x,wv.y,wv.z,wv.w};
#pragma unroll
      for (int i = 0; i < 8; ++i)
#pragma unroll
        for (int j = 0; j < 4; ++j) acc[i][j] += am[i] * wn[j];
    }
    __syncthreads();
  }
  float bv[4];
#pragma unroll
  for (int j = 0; j < 4; ++j) bv[j] = bias[n0 + ng + j];
#pragma unroll
  for (int i = 0; i < 8; ++i) {
    float4 o;
    o.x = acc[i][0] + bv[0]; o.y = acc[i][1] + bv[1];
    o.z = acc[i][2] + bv[2]; o.w = acc[i][3] + bv[3];
    *(float4*)(out + (size_t)(m0 + mg + i) * N + n0 + ng) = o;
  }
}

// fp32 -> bf16 cast, 8 elems/thread.
__global__ __launch_bounds__(256) void k_cast(const float* __restrict__ in,
                                              unsigned short* __restrict__ ob) {
  size_t i = ((size_t)blockIdx.x * 256 + threadIdx.x) * 8;
  const float4* p = (const float4*)(in + i);
  float4 v0 = p[0], v1 = p[1];
  uint4 o;
  o.x = (unsigned)f2bf(v0.x) | ((unsigned)f2bf(v0.y) << 16);
  o.y = (unsigned)f2bf(v0.z) | ((unsigned)f2bf(v0.w) << 16);
  o.z = (unsigned)f2bf(v1.x) | ((unsigned)f2bf(v1.y) << 16);
  o.w = (unsigned)f2bf(v1.z) | ((unsigned)f2bf(v1.w) << 16);
  *(uint4*)(ob + i) = o;
}

// bf16 MFMA NT GEMM (128x128, BK=64, m97 structure) + XOR bank swizzle.
__global__ __launch_bounds__(256) void k_gemm_bf16(
    const unsigned short* __restrict__ A, const unsigned short* __restrict__ W,
    const float* __restrict__ bias, unsigned short* __restrict__ out, int K,
    int N) {
  __shared__ __align__(16) unsigned short As[128 * 64];
  __shared__ __align__(16) unsigned short Ws[128 * 64];
  int t = threadIdx.x, lane = t & 63, wv = t >> 6;
  int nwg = gridDim.x * gridDim.y;
  int lin = blockIdx.y * gridDim.x + blockIdx.x;
  int swz = (lin & 7) * (nwg >> 3) + (lin >> 3);
  int n0 = (swz % gridDim.x) * 128, m0 = (swz / gridDim.x) * 128;
  int wr = wv >> 1, wc = wv & 1;
  f32x4 acc[4][4];
#pragma unroll
  for (int i = 0; i < 4; ++i)
#pragma unroll
    for (int j = 0; j < 4; ++j) acc[i][j] = (f32x4){0.f, 0.f, 0.f, 0.f};
  // staging: LDS slot (row, s) holds global k-chunk s^(row&7); row&7 = (lane>>3)&7
  int scol = ((lane & 7) ^ ((lane >> 3) & 7)) * 8;
  int arow = wr * 64 + (lane & 15), brow = wc * 64 + (lane & 15);
  int ko_ = (lane >> 4) * 8;
  int asw = (lane & 7) << 3;  // (row&7)<<3 for frag reads (arow&7 == lane&7)
  for (int k0 = 0; k0 < K; k0 += 64) {
#pragma unroll
    for (int i = 0; i < 4; ++i) {
      int chunk = wv * 4 + i;
      int row = chunk * 8 + (lane >> 3);
      gload16(A + (size_t)(m0 + row) * K + k0 + scol, &As[chunk * 512]);
      gload16(W + (size_t)(n0 + row) * K + k0 + scol, &Ws[chunk * 512]);
    }
    __syncthreads();
#pragma unroll
    for (int ks = 0; ks < 2; ++ks) {
      bf16x8 af[4], bg[4];
#pragma unroll
      for (int mi = 0; mi < 4; ++mi)
        af[mi] = *(const bf16x8*)&As[(arow + mi * 16) * 64 + ((ks * 32 + ko_) ^ asw)];
#pragma unroll
      for (int ni = 0; ni < 4; ++ni)
        bg[ni] = *(const bf16x8*)&Ws[(brow + ni * 16) * 64 + ((ks * 32 + ko_) ^ asw)];
#pragma unroll
      for (int mi = 0; mi < 4; ++mi)
#pragma unroll
        for (int ni = 0; ni < 4; ++ni)
          acc[mi][ni] = __builtin_amdgcn_mfma_f32_16x16x32_bf16(
              af[mi], bg[ni], acc[mi][ni], 0, 0, 0);
    }
    __syncthreads();
  }
#pragma unroll
  for (int mi = 0; mi < 4; ++mi)
#pragma unroll
    for (int ni = 0; ni < 4; ++ni) {
      int row = m0 + wr * 64 + mi * 16 + (lane >> 4) * 4;
      int col = n0 + wc * 64 + ni * 16 + (lane & 15);
      float bv = bias[col];
#pragma unroll
      for (int j = 0; j < 4; ++j)
        out[(size_t)(row + j) * N + col] = f2bf(acc[mi][ni][j] + bv);
    }
}

// MHA1 probs: scoat[b,c,q] = mean_h softmax_q(qh1[b,c,h]·kh1[b,q,h]*SCALE).
__global__ __launch_bounds__(256) void k_mha1(const float* __restrict__ qh,
                                              const float* __restrict__ kh,
                                              float* __restrict__ scoat) {
  int blk = blockIdx.x;  // b*CL + c
  int b = blk >> 9;
  int t = threadIdx.x, lane = t & 63, h = t >> 6;
  __shared__ float qrow[H_];
  __shared__ float probs[4][64];
#pragma unroll
  for (int j = 0; j < 3; ++j) qrow[t + 256 * j] = qh[(size_t)blk * H_ + t + 256 * j];
  __syncthreads();
  const float* kp = kh + (size_t)(b * QL + lane) * H_ + h * HD;
  const float* qp = &qrow[h * HD];
  float sc = 0.f;
#pragma unroll 4
  for (int k = 0; k < HD; ++k) sc += qp[k] * kp[k];
  sc *= SCALE;
  float M = wave_max(sc);
  float e = expf(sc - M);
  float S = wave_sum(e);
  probs[h][lane] = e / S;
  __syncthreads();
  if (t < 64)
    scoat[(size_t)blk * QL + t] =
        0.25f * (probs[0][t] + probs[1][t] + probs[2][t] + probs[3][t]);
}

// 24-head scores via MFMA: partial head-mean of softmax(qh.kh^T*SCALE).
// Block = (c-tile 16, b, head-group of 12). Per head: q-tile 16x192 + dbuf
// 64-row K-halves (swizzled global_load_lds); acc 8 frags = 16x512 scores;
// in-register softmax (16-lane shfl + LDS cross-wave); macc += e/S/24.
__global__ __launch_bounds__(256) void k_ssm(const unsigned short* __restrict__ qh,
                                             const unsigned short* __restrict__ kh,
                                             float* __restrict__ p0,
                                             float* __restrict__ p1) {
  __shared__ __align__(16) unsigned short qs[16 * 192];
  __shared__ __align__(16) unsigned short ks[2][64 * 192];
  __shared__ float redm[16][4], reds[16][4];
  int b = blockIdx.y, c0 = blockIdx.x * 16;
  int h0 = blockIdx.z * 12;
  float* outp = blockIdx.z ? p1 : p0;
  int t = threadIdx.x, lane = t & 63, wv = t >> 6;
  float macc[8][4];
#pragma unroll
  for (int f = 0; f < 8; ++f)
#pragma unroll
    for (int j = 0; j < 4; ++j) macc[f][j] = 0.f;
  int arow = lane & 15, asw = (arow & 7) << 3, ko = (lane >> 4) * 8;
  int brow = wv * 16 + (lane & 15), bsw = (brow & 7) << 3;
  for (int h = h0; h < h0 + 12; ++h) {
    size_t qbase = (size_t)(b * CL + c0) * E2 + h * HD;
    size_t kbase = (size_t)(b * CL) * E2 + h * HD;
    {  // stage q-tile (384 slots) + k half0 (1536 slots); src k-chunk ^ (row&7)
      int r = t / 24, s0 = t % 24;
      gload16(qh + qbase + (size_t)r * E2 + (s0 ^ (r & 7)) * 8, &qs[(wv * 64) * 8]);
      if (t < 128) {
        int ch2 = 256 + t, r2 = ch2 / 24, s2 = ch2 % 24;
        gload16(qh + qbase + (size_t)r2 * E2 + (s2 ^ (r2 & 7)) * 8,
                &qs[(256 + wv * 64) * 8]);
      }
#pragma unroll
      for (int i = 0; i < 6; ++i) {
        int chk = i * 256 + t, rk = chk / 24, sk = chk % 24;
        gload16(kh + kbase + (size_t)rk * E2 + (sk ^ (rk & 7)) * 8,
                &ks[0][(i * 256 + wv * 64) * 8]);
      }
    }
    __syncthreads();
    bf16x8 af[6];
#pragma unroll
    for (int ks_ = 0; ks_ < 6; ++ks_)
      af[ks_] = *(const bf16x8*)&qs[arow * 192 + ((ks_ * 32 + ko) ^ asw)];
    f32x4 acc[8];
#pragma unroll
    for (int f = 0; f < 8; ++f) acc[f] = (f32x4){0.f, 0.f, 0.f, 0.f};
#pragma unroll 1
    for (int hf = 0; hf < 8; ++hf) {
      if (hf < 7) {  // prefetch next 64-row half into other buffer
        int base = (hf + 1) * 64;
#pragma unroll
        for (int i = 0; i < 6; ++i) {
          int chk = i * 256 + t, rk = chk / 24, sk = chk % 24;
          gload16(kh + kbase + (size_t)(base + rk) * E2 + (sk ^ (rk & 7)) * 8,
                  &ks[(hf + 1) & 1][(i * 256 + wv * 64) * 8]);
        }
      }
      const unsigned short* kb = ks[hf & 1];
#pragma unroll
      for (int ks_ = 0; ks_ < 6; ++ks_) {
        bf16x8 bg = *(const bf16x8*)&kb[brow * 192 + ((ks_ * 32 + ko) ^ bsw)];
        // static index: hf loop body duplicated by compiler? keep acc idx const
        switch (hf) {  // ensure compile-time acc index (rule #20)
          case 0: acc[0] = __builtin_amdgcn_mfma_f32_16x16x32_bf16(af[ks_], bg, acc[0], 0, 0, 0); break;
          case 1: acc[1] = __builtin_amdgcn_mfma_f32_16x16x32_bf16(af[ks_], bg, acc[1], 0, 0, 0); break;
          case 2: acc[2] = __builtin_amdgcn_mfma_f32_16x16x32_bf16(af[ks_], bg, acc[2], 0, 0, 0); break;
          case 3: acc[3] = __builtin_amdgcn_mfma_f32_16x16x32_bf16(af[ks_], bg, acc[3], 0, 0, 0); break;
          case 4: acc[4] = __builtin_amdgcn_mfma_f32_16x16x32_bf16(af[ks_], bg, acc[4], 0, 0, 0); break;
          case 5: acc[5] = __builtin_amdgcn_mfma_f32_16x16x32_bf16(af[ks_], bg, acc[5], 0, 0, 0); break;
          case 6: acc[6] = __builtin_amdgcn_mfma_f32_16x16x32_bf16(af[ks_], bg, acc[6], 0, 0, 0); break;
          case 7: acc[7] = __builtin_amdgcn_mfma_f32_16x16x32_bf16(af[ks_], bg, acc[7], 0, 0, 0); break;
        }
      }
      __syncthreads();  // drains prefetch vmcnt + protects buffer reuse
    }
    // softmax over d=512: rows r=(lane>>4)*4+j; wave holds 128 cols
    float mx[4];
#pragma unroll
    for (int j = 0; j < 4; ++j) {
      float m = acc[0][j];
#pragma unroll
      for (int f = 1; f < 8; ++f) m = fmaxf(m, acc[f][j]);
#pragma unroll
      for (int msk = 1; msk < 16; msk <<= 1) m = fmaxf(m, __shfl_xor(m, msk, 64));
      mx[j] = m;
    }
    if ((lane & 15) == 0) {
#pragma unroll
      for (int j = 0; j < 4; ++j) redm[(lane >> 4) * 4 + j][wv] = mx[j];
    }
    __syncthreads();
    float Mj[4], sm[4];
#pragma unroll
    for (int j = 0; j < 4; ++j) {
      int r = (lane >> 4) * 4 + j;
      Mj[j] = fmaxf(fmaxf(redm[r][0], redm[r][1]), fmaxf(redm[r][2], redm[r][3]));
      sm[j] = 0.f;
    }
#pragma unroll
    for (int f = 0; f < 8; ++f)
#pragma unroll
      for (int j = 0; j < 4; ++j) {
        float e = expf((acc[f][j] - Mj[j]) * SCALE);
        acc[f][j] = e;
        sm[j] += e;
      }
#pragma unroll
    for (int j = 0; j < 4; ++j)
#pragma unroll
      for (int msk = 1; msk < 16; msk <<= 1) sm[j] += __shfl_xor(sm[j], msk, 64);
    if ((lane & 15) == 0) {
#pragma unroll
      for (int j = 0; j < 4; ++j) reds[(lane >> 4) * 4 + j][wv] = sm[j];
    }
    __syncthreads();
#pragma unroll
    for (int j = 0; j < 4; ++j) {
      int r = (lane >> 4) * 4 + j;
      float S = reds[r][0] + reds[r][1] + reds[r][2] + reds[r][3];
      float inv = 1.f / (S * 24.f);
#pragma unroll
      for (int f = 0; f < 8; ++f) macc[f][j] += acc[f][j] * inv;
    }
  }
#pragma unroll
  for (int f = 0; f < 8; ++f)
#pragma unroll
    for (int j = 0; j < 4; ++j) {
      int r = c0 + (lane >> 4) * 4 + j;
      int col = f * 64 + wv * 16 + (lane & 15);
      outp[(size_t)(b * CL + r) * CL + col] = macc[f][j];
    }
}

// ss = p0+p1; masked softmax over c (512 rows) per (b,d-col); bf16 out.
__global__ __launch_bounds__(256) void k_colsm2bf(
    const float* __restrict__ p0, const float* __restrict__ p1,
    const int* __restrict__ cmask, unsigned short* __restrict__ ob) {
  int b = blockIdx.y;
  int t = threadIdx.x, lane = t & 63, wv = t >> 6;
  int col = blockIdx.x * 16 + (lane & 15);
  int rsub = lane >> 4;  // 0..3
  __shared__ float rm[4][16], rs[4][16];
  const float* q0 = p0 + (size_t)b * CL * CL + col;
  const float* q1 = p1 + (size_t)b * CL * CL + col;
  const int* mp = cmask + b * CL;
  float m = NEGV;
  for (int it = 0; it < 32; ++it) {
    int r = wv * 128 + rsub + it * 4;
    float v = mp[r] ? (q0[(size_t)r * CL] + q1[(size_t)r * CL]) : NEGV;
    m = fmaxf(m, v);
  }
  m = fmaxf(m, __shfl_xor(m, 16, 64));
  m = fmaxf(m, __shfl_xor(m, 32, 64));
  if (lane < 16) rm[wv][lane] = m;
  __syncthreads();
  float M = fmaxf(fmaxf(rm[0][lane & 15], rm[1][lane & 15]),
                  fmaxf(rm[2][lane & 15], rm[3][lane & 15]));
  float s = 0.f;
  for (int it = 0; it < 32; ++it) {
    int r = wv * 128 + rsub + it * 4;
    float v = mp[r] ? (q0[(size_t)r * CL] + q1[(size_t)r * CL]) : NEGV;
    s += expf(v - M);
  }
  s += __shfl_xor(s, 16, 64);
  s += __shfl_xor(s, 32, 64);
  if (lane < 16) rs[wv][lane] = s;
  __syncthreads();
  float S = rs[0][lane & 15] + rs[1][lane & 15] + rs[2][lane & 15] + rs[3][lane & 15];
  float inv = 1.f / S;
  unsigned short* op = ob + (size_t)b * CL * CL + col;
  for (int it = 0; it < 32; ++it) {
    int r = wv * 128 + rsub + it * 4;
    float v = mp[r] ? (q0[(size_t)r * CL] + q1[(size_t)r * CL]) : NEGV;
    op[(size_t)r * CL] = f2bf(expf(v - M) * inv);
  }
}

// bf16 MFMA NN GEMM: out[b,c,e] += sum_d ss1b[b,c,d] * ybf[b,d,e].
// A staged via swizzled global_load_lds; B (64d x 128e) reg-transposed into
// Bs[e][64d] with XOR swizzle (2x2 uint pack -> ds_write_b32, 2-way banks).
__global__ __launch_bounds__(256) void k_gemm_nn(
    const unsigned short* __restrict__ A, const unsigned short* __restrict__ Bm,
    float* __restrict__ out) {
  __shared__ __align__(16) unsigned short As[128 * 64];
  __shared__ __align__(16) unsigned short Bs[128 * 64];
  int b = blockIdx.z;
  int n0 = blockIdx.x * 128, m0 = blockIdx.y * 128;
  int t = threadIdx.x, lane = t & 63, wv = t >> 6;
  int wr = wv >> 1, wc = wv & 1;
  f32x4 acc[4][4];
#pragma unroll
  for (int i = 0; i < 4; ++i)
#pragma unroll
    for (int j = 0; j < 4; ++j) acc[i][j] = (f32x4){0.f, 0.f, 0.f, 0.f};
  int sA = ((lane & 7) ^ ((lane >> 3) & 7)) * 8;
  int bd = (t & 31) * 2, be = (t >> 5) * 16;
  int arow = wr * 64 + (lane & 15), brow = wc * 64 + (lane & 15);
  int ko = (lane >> 4) * 8, asw = (lane & 7) << 3;
  unsigned* bs32 = (unsigned*)Bs;
  for (int k0 = 0; k0 < CL; k0 += 64) {
#pragma unroll
    for (int i = 0; i < 4; ++i) {
      int chunk = wv * 4 + i, row = chunk * 8 + (lane >> 3);
      gload16(A + (size_t)(b * CL + m0 + row) * CL + k0 + sA, &As[chunk * 512]);
    }
    {  // B: rows bd, bd+1; cols be..be+15
      const unsigned short* bp = Bm + (size_t)(b * CL + k0 + bd) * E2 + n0 + be;
      uint4 ra = *(const uint4*)bp;
      uint4 rb = *(const uint4*)(bp + 8);
      uint4 rc = *(const uint4*)(bp + E2);
      uint4 rd = *(const uint4*)(bp + E2 + 8);
      unsigned a0[4] = {ra.x, ra.y, ra.z, ra.w};
      unsigned c0_[4] = {rc.x, rc.y, rc.z, rc.w};
      unsigned a1[4] = {rb.x, rb.y, rb.z, rb.w};
      unsigned c1[4] = {rd.x, rd.y, rd.z, rd.w};
#pragma unroll
      for (int j = 0; j < 8; ++j) {
        int e = be + j;
        unsigned lo = (a0[j >> 1] >> ((j & 1) * 16)) & 0xffffu;
        unsigned hi = (c0_[j >> 1] >> ((j & 1) * 16)) & 0xffffu;
        bs32[e * 32 + ((bd >> 1) ^ ((e & 7) << 2))] = lo | (hi << 16);
      }
#pragma unroll
      for (int j = 0; j < 8; ++j) {
        int e = be + 8 + j;
        unsigned lo = (a1[j >> 1] >> ((j & 1) * 16)) & 0xffffu;
        unsigned hi = (c1[j >> 1] >> ((j & 1) * 16)) & 0xffffu;
        bs32[e * 32 + ((bd >> 1) ^ ((e & 7) << 2))] = lo | (hi << 16);
      }
    }
    __syncthreads();
#pragma unroll
    for (int ks_ = 0; ks_ < 2; ++ks_) {
      bf16x8 af[4], bg[4];
#pragma unroll
      for (int mi = 0; mi < 4; ++mi)
        af[mi] = *(const bf16x8*)&As[(arow + mi * 16) * 64 + ((ks_ * 32 + ko) ^ asw)];
#pragma unroll
      for (int ni = 0; ni < 4; ++ni)
        bg[ni] = *(const bf16x8*)&Bs[(brow + ni * 16) * 64 + ((ks_ * 32 + ko) ^ asw)];
#pragma unroll
      for (int mi = 0; mi < 4; ++mi)
#pragma unroll
        for (int ni = 0; ni < 4; ++ni)
          acc[mi][ni] = __builtin_amdgcn_mfma_f32_16x16x32_bf16(
              af[mi], bg[ni], acc[mi][ni], 0, 0, 0);
    }
    __syncthreads();
  }
#pragma unroll
  for (int mi = 0; mi < 4; ++mi)
#pragma unroll
    for (int ni = 0; ni < 4; ++ni) {
      int row = m0 + wr * 64 + mi * 16 + (lane >> 4) * 4;
      int col = n0 + wc * 64 + ni * 16 + (lane & 15);
#pragma unroll
      for (int j = 0; j < 4; ++j) {
        size_t idx = (size_t)(b * CL + row + j) * E2 + col;
        out[idx] += acc[mi][ni][j];
      }
    }
}

// concat x -> d_out; layernorm -> ybf (bf16 only; fp32 y dropped).
__global__ __launch_bounds__(256) void k_xln(
    const float* __restrict__ c, const float* __restrict__ a,
    const float* __restrict__ bf, const float* __restrict__ s3,
    const float* __restrict__ ac, const float* __restrict__ gamma,
    const float* __restrict__ beta, float* __restrict__ xout,
    unsigned short* __restrict__ ybf) {
  int row = blockIdx.x, t = threadIdx.x, lane = t & 63, wv = t >> 6;
  size_t base = (size_t)row * H_;
  float xs[6][3];
  float sum = 0.f, sq = 0.f;
#pragma unroll
  for (int kk = 0; kk < 3; ++kk) {
    int j = t + kk * 256;
    float cv = c[base + j], av = a[base + j], bv = bf[base + j];
    float sv = s3[base + j], av2 = ac[base + j];
    xs[0][kk] = cv; xs[1][kk] = av; xs[2][kk] = cv * av;
    xs[3][kk] = cv * bv; xs[4][kk] = sv; xs[5][kk] = av2;
  }
#pragma unroll
  for (int s = 0; s < 6; ++s)
#pragma unroll
    for (int kk = 0; kk < 3; ++kk) {
      sum += xs[s][kk];
      sq += xs[s][kk] * xs[s][kk];
    }
  sum = wave_sum(sum);
  sq = wave_sum(sq);
  __shared__ float red[4][2];
  if (lane == 0) { red[wv][0] = sum; red[wv][1] = sq; }
  __syncthreads();
  float TS = red[0][0] + red[1][0] + red[2][0] + red[3][0];
  float TQ = red[0][1] + red[1][1] + red[2][1] + red[3][1];
  float mu = TS * (1.f / (float)E2);
  float var = TQ * (1.f / (float)E2) - mu * mu;
  float rstd = rsqrtf(var + 1e-5f);
  size_t obase = (size_t)row * E2;
#pragma unroll
  for (int s = 0; s < 6; ++s)
#pragma unroll
    for (int kk = 0; kk < 3; ++kk) {
      int col = s * H_ + t + kk * 256;
      float xv = xs[s][kk];
      float yv = (xv - mu) * rstd * gamma[col] + beta[col];
      xout[obase + col] = xv;
      ybf[obase + col] = f2bf(yv);
    }
}

extern "C" void kernel_launch(void* const* d_in, const int* in_sizes, int n_in,
                              void* d_out, int out_size, void* d_ws,
                              size_t ws_size, hipStream_t stream) {
  const float* c = (const float*)d_in[0];
  const float* q = (const float*)d_in[1];
  const int* c_mask = (const int*)d_in[2];
  const int* q_mask = (const int*)d_in[3];
  const float* c_weight = (const float*)d_in[4];
  const float* q_weight = (const float*)d_in[5];
  const float* cq_weight = (const float*)d_in[6];
  const float* bias = (const float*)d_in[7];
  const float* wq1 = (const float*)d_in[8];
  const float* bq1 = (const float*)d_in[9];
  const float* wk1 = (const float*)d_in[10];
  const float* bk1 = (const float*)d_in[11];
  const float* gamma = (const float*)d_in[12];
  const float* beta = (const float*)d_in[13];
  const float* wq2 = (const float*)d_in[14];
  const float* bq2 = (const float*)d_in[15];
  const float* wk2 = (const float*)d_in[16];
  const float* bk2 = (const float*)d_in[17];
  float* out = (float*)d_out;

  // ---- workspace (bytes): persistent 176.7MB, early aliased. ----
  char* wsb = (char*)d_ws;
  unsigned short* ybf  = (unsigned short*)wsb;                   // 37,748,736
  unsigned short* qh2b = (unsigned short*)(wsb + 37748736);      // 37,748,736
  unsigned short* kh2b = (unsigned short*)(wsb + 75497472);      // 37,748,736
  unsigned short* wbf  = (unsigned short*)(wsb + 113246208);     // 42,467,328
  float* p0   = (float*)(wsb + 155713536);                       //  8,388,608
  float* p1   = (float*)(wsb + 164102144);                       //  8,388,608
  unsigned short* ss1b = (unsigned short*)(wsb + 172490752);     //  4,194,304
  // early fp32 buffers (dead before stage 16) inside [qh2b, kh2b) region:
  float* e = (float*)(wsb + 37748736);
  float* s      = e; e += 262144;
  float* s1m    = e; e += 262144;
  float* s2m    = e; e += 262144;
  float* scoatb = e; e += 262144;
  float* scoat1 = e; e += 262144;
  float* scoat2 = e; e += 262144;
  float* s0buf  = e; e += 4096;
  float* s1buf  = e; e += 512;
  float* qh1    = e; e += 3145728;
  float* kh1    = e; e += 393216;
  float* U_     = e; e += 393216;
  float* bcoat  = e; e += 393216;
  float* a_     = e; e += 3145728;
  float* bfull  = e; e += 3145728;
  float* acoat  = e; e += 3145728;
  float* scoat3 = e; e += 3145728;  // ends at 37.7M + 73.9M = 111.6M < 113.2M

  // 1. s0, s1 row dots
  k_rowdot<<<B_ * CL / 4, 256, 0, stream>>>(c, c_weight, s0buf, H_);
  k_rowdot<<<B_ * QL / 4, 256, 0, stream>>>(q, q_weight, s1buf, H_);
  // 2. s
  k_s_assemble<<<dim3(CL / 32, B_), 256, 0, stream>>>(c, q, cq_weight, s0buf,
                                                      s1buf, bias, s);
  // 3-4. masked softmaxes
  k_rowsm64<<<B_ * CL / 4, 256, 0, stream>>>(s, q_mask, s1m);
  k_colsm<<<dim3(QL, B_), 256, 0, stream>>>(s, c_mask, s2m, QL);
  // 5-7. a, U = s2m^T@c, b = s1m@U
  k_gemm_bt<<<dim3(H_ / 64, CL / 32, B_), 256, 0, stream>>>(s1m, q, a_, CL, QL, H_, 0, 0);
  k_gemm_bt<<<dim3(H_ / 64, QL / 32, B_), 256, 0, stream>>>(s2m, c, U_, QL, CL, H_, 1, 0);
  k_gemm_bt<<<dim3(H_ / 64, CL / 32, B_), 256, 0, stream>>>(s1m, U_, bfull, CL, QL, H_, 0, 0);
  // 8. qh1, kh1 (small fp32 NT GEMMs)
  k_gemm_nt<<<dim3(H_ / 64, B_ * CL / 128), 256, 0, stream>>>(c, wq1, bq1, qh1, H_, H_);
  k_gemm_nt<<<dim3(H_ / 64, B_ * QL / 128), 256, 0, stream>>>(q, wk1, bk1, kh1, H_, H_);
  // 9-11. scoat + masked softmaxes
  k_mha1<<<B_ * CL, 256, 0, stream>>>(qh1, kh1, scoatb);
  k_rowsm64<<<B_ * CL / 4, 256, 0, stream>>>(scoatb, q_mask, scoat1);
  k_colsm<<<dim3(QL, B_), 256, 0, stream>>>(scoatb, c_mask, scoat2, QL);
  // 12-14. acoat, bcoat, scoat3
  k_gemm_bt<<<dim3(H_ / 64, CL / 32, B_), 256, 0, stream>>>(scoat1, q, acoat, CL, QL, H_, 0, 0);
  k_gemm_bt<<<dim3(H_ / 64, QL / 32, B_), 256, 0, stream>>>(scoat2, c, bcoat, QL, CL, H_, 1, 0);
  k_gemm_bt<<<dim3(H_ / 64, CL / 32, B_), 256, 0, stream>>>(scoat1, bcoat, scoat3, CL, QL, H_, 0, 0);
  // 15. x (-> d_out) + layernorm -> ybf
  k_xln<<<B_ * CL, 256, 0, stream>>>(c, a_, bfull, scoat3, acoat, gamma, beta,
                                     out, ybf);
  // 16. casts + big bf16 MFMA GEMMs
  k_cast<<<E2 * E2 / 2048, 256, 0, stream>>>(wq2, wbf);
  k_gemm_bf16<<<dim3(E2 / 128, B_ * CL / 128), 256, 0, stream>>>(ybf, wbf, bq2,
                                                                 qh2b, E2, E2);
  k_cast<<<E2 * E2 / 2048, 256, 0, stream>>>(wk2, wbf);
  k_gemm_bf16<<<dim3(E2 / 128, B_ * CL / 128), 256, 0, stream>>>(ybf, wbf, bk2,
                                                                 kh2b, E2, E2);
  // 17. 24-head scores via MFMA (head-split partials)
  k_ssm<<<dim3(CL / 16, B_, 2), 256, 0, stream>>>(qh2b, kh2b, p0, p1);
  // 18. ss = p0+p1 -> masked col softmax -> ss1b (bf16)
  k_colsm2bf<<<dim3(CL / 16, B_), 256, 0, stream>>>(p0, p1, c_mask, ss1b);
  // 19. patt = ss1b @ ybf + x (x already in d_out)
  k_gemm_nn<<<dim3(E2 / 128, CL / 128, B_), 256, 0, stream>>>(ss1b, ybf, out);
}

// Round 9
// 1310.970 us; speedup vs baseline: 4.9556x; 1.2584x over previous
//
// QANet-style fused attention block, MI355X. R9 == R4 resubmit (R4..R8 all
// GPUAcquisitionTimeout — broker at capacity; changes still unverified).
// Journal: R1 fp32 6497us; R2 bf16 big GEMMs 2861us; R3 MFMA k_ss/nn 1650us
// (absmax 0.03125). R3 top: k_gemm_bf16 2x329us @529TF (MfmaUtil 22%, conflicts
// 0, HBM 19% -> barrier-drain bound; staging drained BEFORE compute).
// R4..R9: (1) big GEMMs -> 2-phase dbuf schedule {STAGE(next); compute(cur); bar}
// (catalog T3-min, m228d/m230 622-682TF) + setprio; (2) qh1/kh1 -> bf16 MFMA
// (k_cast4 for c/q/wq1/wk1), drops fp32 k_gemm_nt; (3) k_mha1b: LDS-staged
// kh1-in-regs version (786MB L2 traffic -> 25MB).
// WS: persistent 193.2MB (adds cb/qb/w1qb/w1kb/qh1b/kh1b after ss1b); early
// fp32 bufs (59.8MB) alias [qh2b..] dead-until-stage-16 region. <=243.3MB proven.
#include <hip/hip_runtime.h>

#define B_ 8
#define CL 512
#define QL 64
#define H_ 768
#define E2 4608
#define NH2 24
#define HD 192
#define NEGV -1e30f
#define SCALE 0.07216878364870323f  // 1/sqrt(192)

typedef __attribute__((ext_vector_type(8))) short bf16x8;
typedef __attribute__((ext_vector_type(4))) float f32x4;

__device__ __forceinline__ float wave_max(float v) {
#pragma unroll
  for (int m = 32; m >= 1; m >>= 1) v = fmaxf(v, __shfl_xor(v, m, 64));
  return v;
}
__device__ __forceinline__ float wave_sum(float v) {
#pragma unroll
  for (int m = 32; m >= 1; m >>= 1) v += __shfl_xor(v, m, 64);
  return v;
}
__device__ __forceinline__ unsigned short f2bf(float f) {
  union { float f; unsigned u; } a; a.f = f;
  unsigned u = a.u;
  unsigned r = u + 0x7fffu + ((u >> 16) & 1u);  // RNE
  return (unsigned short)(r >> 16);
}
__device__ __forceinline__ float bf2f(unsigned short s) {
  return __uint_as_float(((unsigned)s) << 16);
}
__device__ __forceinline__ void gload16(const void* g, void* l) {
  __builtin_amdgcn_global_load_lds(
      (const __attribute__((address_space(1))) unsigned int*)g,
      (__attribute__((address_space(3))) unsigned int*)l, 16, 0, 0);
}

// out[r] = dot(in[r, :K], w[:K]); one wave per row.
__global__ __launch_bounds__(256) void k_rowdot(const float* __restrict__ in,
                                                const float* __restrict__ w,
                                                float* __restrict__ out, int K) {
  int t = threadIdx.x, lane = t & 63, wv = t >> 6;
  int row = blockIdx.x * 4 + wv;
  const float* ip = in + (size_t)row * K;
  float s = 0.f;
  for (int j = lane; j < K; j += 64) s += ip[j] * w[j];
  s = wave_sum(s);
  if (lane == 0) out[row] = s;
}

// s[b,c,q] = s0[b,c] + s1[b,q] + sum_h c[b,c,h]*cqw[h]*q[b,q,h] + bias
__global__ __launch_bounds__(256) void k_s_assemble(
    const float* __restrict__ c, const float* __restrict__ q,
    const float* __restrict__ cqw, const float* __restrict__ s0,
    const float* __restrict__ s1, const float* __restrict__ bias,
    float* __restrict__ s) {
  int b = blockIdx.y, c0 = blockIdx.x * 32;
  int t = threadIdx.x, qq = t & 63, grp = t >> 6;
  __shared__ float qs[64][33];
  __shared__ float cs[32][33];
  float acc[8] = {};
  int qr = t >> 2, qc = (t & 3) * 8;
  for (int k0 = 0; k0 < H_; k0 += 32) {
    float qbuf[8], cbuf[8] = {};
    {
      const float4* qp = (const float4*)(q + (size_t)(b * QL + qr) * H_ + k0 + qc);
      float4 q0 = qp[0], q1 = qp[1];
      qbuf[0]=q0.x; qbuf[1]=q0.y; qbuf[2]=q0.z; qbuf[3]=q0.w;
      qbuf[4]=q1.x; qbuf[5]=q1.y; qbuf[6]=q1.z; qbuf[7]=q1.w;
    }
    if (t < 128) {
      int cr = t >> 2, cc = (t & 3) * 8;
      const float4* cp = (const float4*)(c + (size_t)(b * CL + c0 + cr) * H_ + k0 + cc);
      float4 c0v = cp[0], c1v = cp[1];
      float tmp[8] = {c0v.x,c0v.y,c0v.z,c0v.w,c1v.x,c1v.y,c1v.z,c1v.w};
#pragma unroll
      for (int j = 0; j < 8; ++j) cbuf[j] = tmp[j] * cqw[k0 + cc + j];
    }
    __syncthreads();
#pragma unroll
    for (int j = 0; j < 8; ++j) qs[qr][qc + j] = qbuf[j];
    if (t < 128) {
      int cr = t >> 2, cc = (t & 3) * 8;
#pragma unroll
      for (int j = 0; j < 8; ++j) cs[cr][cc + j] = cbuf[j];
    }
    __syncthreads();
#pragma unroll
    for (int kk = 0; kk < 32; ++kk) {
      float qv = qs[qq][kk];
#pragma unroll
      for (int i = 0; i < 8; ++i) acc[i] += cs[grp * 8 + i][kk] * qv;
    }
    __syncthreads();
  }
  float s1v = s1[b * QL + qq], b0 = bias[0];
#pragma unroll
  for (int i = 0; i < 8; ++i) {
    int cc = c0 + grp * 8 + i;
    s[(size_t)(b * CL + cc) * QL + qq] = acc[i] + s0[b * CL + cc] + s1v + b0;
  }
}

// masked softmax over last axis (len 64), mask = q_mask[b, q]; 1 wave/row.
__global__ __launch_bounds__(256) void k_rowsm64(const float* __restrict__ in,
                                                 const int* __restrict__ qmask,
                                                 float* __restrict__ out) {
  int t = threadIdx.x, lane = t & 63, wv = t >> 6;
  int row = blockIdx.x * 4 + wv;  // b*CL + c
  int b = row >> 9;
  float x = in[(size_t)row * QL + lane];
  float v = qmask[b * QL + lane] ? x : NEGV;
  float M = wave_max(v);
  float e = expf(v - M);
  float S = wave_sum(e);
  out[(size_t)row * QL + lane] = e / S;
}

// masked softmax over axis-1 (rows, len CL) for each (b, col); C=QL here.
__global__ __launch_bounds__(256) void k_colsm(const float* __restrict__ in,
                                               const int* __restrict__ cmask,
                                               float* __restrict__ out, int C) {
  int b = blockIdx.y, col = blockIdx.x, t = threadIdx.x;
  int lane = t & 63, wv = t >> 6;
  const float* ip = in + (size_t)b * CL * C + col;
  float* op = out + (size_t)b * CL * C + col;
  const int* mp = cmask + b * CL;
  float v0 = mp[t] ? ip[(size_t)t * C] : NEGV;
  float v1 = mp[t + 256] ? ip[(size_t)(t + 256) * C] : NEGV;
  __shared__ float red[4];
  float m = wave_max(fmaxf(v0, v1));
  if (lane == 0) red[wv] = m;
  __syncthreads();
  float M = fmaxf(fmaxf(red[0], red[1]), fmaxf(red[2], red[3]));
  __syncthreads();
  float e0 = expf(v0 - M), e1 = expf(v1 - M);
  float s = wave_sum(e0 + e1);
  if (lane == 0) red[wv] = s;
  __syncthreads();
  float S = red[0] + red[1] + red[2] + red[3];
  op[(size_t)t * C] = e0 / S;
  op[(size_t)(t + 256) * C] = e1 / S;
}

// Batched fp32 GEMM for the small QL-K products (stages 5-7, 12-14).
__global__ __launch_bounds__(256) void k_gemm_bt(const float* __restrict__ A,
                                                 const float* __restrict__ Bm,
                                                 float* __restrict__ out, int M,
                                                 int K, int N, int ta, int addout) {
  int b = blockIdx.z;
  int n0 = blockIdx.x * 64, m0 = blockIdx.y * 32;
  const float* Ab = A + (size_t)b * M * K;
  const float* Bb = Bm + (size_t)b * K * N;
  float* Ob = out + (size_t)b * M * N;
  int t = threadIdx.x, lane = t & 63, mg = (t >> 6) * 8;
  __shared__ float As[32][36];
  __shared__ float Bs[32][64];
  float acc[8] = {};
  for (int k0 = 0; k0 < K; k0 += 32) {
    float4 av; float4 bv0, bv1;
    if (!ta) {
      int r = t >> 3, cc = (t & 7) * 4;
      av = *(const float4*)(Ab + (size_t)(m0 + r) * K + k0 + cc);
    } else {
      int kk = t >> 3, r4 = (t & 7) * 4;
      av = *(const float4*)(Ab + (size_t)(k0 + kk) * M + m0 + r4);
    }
    {
      int kk = t >> 3, n8 = (t & 7) * 8;
      const float4* bp = (const float4*)(Bb + (size_t)(k0 + kk) * N + n0 + n8);
      bv0 = bp[0]; bv1 = bp[1];
    }
    __syncthreads();
    if (!ta) {
      int r = t >> 3, cc = (t & 7) * 4;
      As[r][cc] = av.x; As[r][cc + 1] = av.y; As[r][cc + 2] = av.z; As[r][cc + 3] = av.w;
    } else {
      int kk = t >> 3, r4 = (t & 7) * 4;
      As[r4][kk] = av.x; As[r4 + 1][kk] = av.y; As[r4 + 2][kk] = av.z; As[r4 + 3][kk] = av.w;
    }
    {
      int kk = t >> 3, n8 = (t & 7) * 8;
      float tmp[8] = {bv0.x,bv0.y,bv0.z,bv0.w,bv1.x,bv1.y,bv1.z,bv1.w};
#pragma unroll
      for (int j = 0; j < 8; ++j) Bs[kk][n8 + j] = tmp[j];
    }
    __syncthreads();
#pragma unroll 4
    for (int kk = 0; kk < 32; ++kk) {
      float bv = Bs[kk][lane];
#pragma unroll
      for (int i = 0; i < 8; ++i) acc[i] += As[mg + i][kk] * bv;
    }
    __syncthreads();
  }
#pragma unroll
  for (int i = 0; i < 8; ++i) {
    size_t idx = (size_t)(m0 + mg + i) * N + n0 + lane;
    Ob[idx] = acc[i] + (addout ? Ob[idx] : 0.f);
  }
}

// fp32 -> bf16 cast, 8 elems/thread.
__global__ __launch_bounds__(256) void k_cast(const float* __restrict__ in,
                                              unsigned short* __restrict__ ob) {
  size_t i = ((size_t)blockIdx.x * 256 + threadIdx.x) * 8;
  const float4* p = (const float4*)(in + i);
  float4 v0 = p[0], v1 = p[1];
  uint4 o;
  o.x = (unsigned)f2bf(v0.x) | ((unsigned)f2bf(v0.y) << 16);
  o.y = (unsigned)f2bf(v0.z) | ((unsigned)f2bf(v0.w) << 16);
  o.z = (unsigned)f2bf(v1.x) | ((unsigned)f2bf(v1.y) << 16);
  o.w = (unsigned)f2bf(v1.z) | ((unsigned)f2bf(v1.w) << 16);
  *(uint4*)(ob + i) = o;
}

// 4-segment fused cast (c, q, wq1, wk1). Block counts: 1536/192/288/288.
__global__ __launch_bounds__(256) void k_cast4(
    const float* __restrict__ s0, unsigned short* __restrict__ d0, int n0,
    const float* __restrict__ s1, unsigned short* __restrict__ d1, int n1,
    const float* __restrict__ s2, unsigned short* __restrict__ d2, int n2,
    const float* __restrict__ s3, unsigned short* __restrict__ d3) {
  int bx = blockIdx.x;
  const float* sp; unsigned short* dp; int off;
  if (bx < n0) { sp = s0; dp = d0; off = bx; }
  else if (bx < n0 + n1) { sp = s1; dp = d1; off = bx - n0; }
  else if (bx < n0 + n1 + n2) { sp = s2; dp = d2; off = bx - n0 - n1; }
  else { sp = s3; dp = d3; off = bx - n0 - n1 - n2; }
  size_t i = ((size_t)off * 256 + threadIdx.x) * 8;
  const float4* p = (const float4*)(sp + i);
  float4 v0 = p[0], v1 = p[1];
  uint4 o;
  o.x = (unsigned)f2bf(v0.x) | ((unsigned)f2bf(v0.y) << 16);
  o.y = (unsigned)f2bf(v0.z) | ((unsigned)f2bf(v0.w) << 16);
  o.z = (unsigned)f2bf(v1.x) | ((unsigned)f2bf(v1.y) << 16);
  o.w = (unsigned)f2bf(v1.z) | ((unsigned)f2bf(v1.w) << 16);
  *(uint4*)(dp + i) = o;
}

// bf16 MFMA NT GEMM, 2-phase dbuf schedule (catalog T3-minimum):
// { STAGE(next); ds_read+MFMA(cur) with setprio; __syncthreads } per K-tile.
// 128x128 tile, BK=64, 4 waves 2x2, zero-conflict XOR swizzle (R3-proven),
// XCD-aware block swizzle (guarded bijective). out = bf16(A@W^T + bias).
__global__ __launch_bounds__(256, 2) void k_gemm_2ph(
    const unsigned short* __restrict__ A, const unsigned short* __restrict__ W,
    const float* __restrict__ bias, unsigned short* __restrict__ out, int K,
    int N) {
  __shared__ __align__(16) unsigned short AsB[2][128 * 64];
  __shared__ __align__(16) unsigned short WsB[2][128 * 64];
  int t = threadIdx.x, lane = t & 63, wv = t >> 6;
  int nwg = gridDim.x * gridDim.y;
  int lin = blockIdx.y * gridDim.x + blockIdx.x;
  int swz = ((nwg & 7) == 0) ? ((lin & 7) * (nwg >> 3) + (lin >> 3)) : lin;
  int n0 = (swz % gridDim.x) * 128, m0 = (swz / gridDim.x) * 128;
  int wr = wv >> 1, wc = wv & 1;
  f32x4 acc[4][4];
#pragma unroll
  for (int i = 0; i < 4; ++i)
#pragma unroll
    for (int j = 0; j < 4; ++j) acc[i][j] = (f32x4){0.f, 0.f, 0.f, 0.f};
  // staging: slot = i*256+t; row = i*32+(t>>3); LDS chunk t&7 holds global
  // chunk (t&7)^(row&7) -> frag reads use same involution (0 conflicts, R3).
  int sgl = ((t & 7) ^ ((t >> 3) & 7)) * 8;
  const unsigned short* Ag = A + (size_t)(m0 + (t >> 3)) * K + sgl;
  const unsigned short* Wg = W + (size_t)(n0 + (t >> 3)) * K + sgl;
  int ldsb = (wv * 64) * 8;

#define STAGE2(buf, k0)                                                     \
  {                                                                         \
    _Pragma("unroll") for (int i = 0; i < 4; ++i) {                         \
      gload16(Ag + (size_t)(i * 32) * K + (k0), &AsB[buf][i * 2048 + ldsb]);\
      gload16(Wg + (size_t)(i * 32) * K + (k0), &WsB[buf][i * 2048 + ldsb]);\
    }                                                                       \
  }

  STAGE2(0, 0);
  __syncthreads();  // auto vmcnt(0) drain: tile 0 visible
  int nt = K >> 6;
  int ar_ = wr * 64 + (lane & 15), br_ = wc * 64 + (lane & 15);
  for (int tt = 0; tt < nt; ++tt) {
    int cur = tt & 1;
    if (tt + 1 < nt) STAGE2(cur ^ 1, (tt + 1) << 6);  // issue-early prefetch
    const unsigned short* Ab = AsB[cur];
    const unsigned short* Wb = WsB[cur];
    __builtin_amdgcn_s_setprio(1);
#pragma unroll
    for (int ks = 0; ks < 2; ++ks) {
      int kx = ((ks * 4 + (lane >> 4)) ^ (lane & 7)) * 8;
      bf16x8 af[4], bg[4];
#pragma unroll
      for (int mi = 0; mi < 4; ++mi)
        af[mi] = *(const bf16x8*)&Ab[(ar_ + mi * 16) * 64 + kx];
#pragma unroll
      for (int ni = 0; ni < 4; ++ni)
        bg[ni] = *(const bf16x8*)&Wb[(br_ + ni * 16) * 64 + kx];
#pragma unroll
      for (int mi = 0; mi < 4; ++mi)
#pragma unroll
        for (int ni = 0; ni < 4; ++ni)
          acc[mi][ni] = __builtin_amdgcn_mfma_f32_16x16x32_bf16(
              af[mi], bg[ni], acc[mi][ni], 0, 0, 0);
    }
    __builtin_amdgcn_s_setprio(0);
    __syncthreads();  // drains prefetch vmcnt + frees cur for next STAGE
  }
#pragma unroll
  for (int mi = 0; mi < 4; ++mi)
#pragma unroll
    for (int ni = 0; ni < 4; ++ni) {
      int row = m0 + wr * 64 + mi * 16 + (lane >> 4) * 4;
      int col = n0 + wc * 64 + ni * 16 + (lane & 15);
      float bv = bias[col];
#pragma unroll
      for (int j = 0; j < 4; ++j)
        out[(size_t)(row + j) * N + col] = f2bf(acc[mi][ni][j] + bv);
    }
#undef STAGE2
}

// MHA1 probs, bf16: scoat[b,c,q] = mean_h softmax_q(qh1b.kh1b/sqrt(192)).
// Block = (b, 16 c-rows); kh1b row held in 24 bf16x8 regs per lane (lane=q,
// wave=head); qh1b c-tile staged in LDS, broadcast reads.
__global__ __launch_bounds__(256) void k_mha1b(
    const unsigned short* __restrict__ qh, const unsigned short* __restrict__ kh,
    float* __restrict__ scoat) {
  __shared__ __align__(16) unsigned short qs_[16 * H_];  // 24KB
  __shared__ float pb[16][4][64];                        // 16KB
  int b = blockIdx.y, c0 = blockIdx.x * 16;
  int t = threadIdx.x, lane = t & 63, h = t >> 6;
  // stage q-tile: 1536 chunks of 8 bf16; linear LDS (broadcast reads later)
#pragma unroll
  for (int i = 0; i < 6; ++i) {
    int cs = i * 256 + t, row = cs / 96, ch = cs % 96;
    gload16(qh + (size_t)(b * CL + c0 + row) * H_ + ch * 8,
            &qs_[(i * 256 + h * 64) * 8]);
  }
  bf16x8 kr[24];
  const unsigned short* kp = kh + (size_t)(b * QL + lane) * H_ + h * HD;
#pragma unroll
  for (int j = 0; j < 24; ++j) kr[j] = *(const bf16x8*)(kp + j * 8);
  __syncthreads();  // drains gload_lds
  for (int c = 0; c < 16; ++c) {
    const unsigned short* qp = &qs_[c * H_ + h * HD];
    float sc = 0.f;
#pragma unroll
    for (int j = 0; j < 24; ++j) {
      bf16x8 qv = *(const bf16x8*)(qp + j * 8);
#pragma unroll
      for (int e = 0; e < 8; ++e)
        sc += bf2f((unsigned short)qv[e]) * bf2f((unsigned short)kr[j][e]);
    }
    sc *= SCALE;
    float M = wave_max(sc);
    float e = expf(sc - M);
    float S = wave_sum(e);
    pb[c][h][lane] = e / S;
  }
  __syncthreads();
#pragma unroll
  for (int i = 0; i < 4; ++i) {
    int idx = i * 256 + t, c = idx >> 6, q = idx & 63;
    scoat[(size_t)(b * CL + c0 + c) * QL + q] =
        0.25f * (pb[c][0][q] + pb[c][1][q] + pb[c][2][q] + pb[c][3][q]);
  }
}

// 24-head scores via MFMA: partial head-mean of softmax(qh.kh^T*SCALE).
__global__ __launch_bounds__(256) void k_ssm(const unsigned short* __restrict__ qh,
                                             const unsigned short* __restrict__ kh,
                                             float* __restrict__ p0,
                                             float* __restrict__ p1) {
  __shared__ __align__(16) unsigned short qs[16 * 192];
  __shared__ __align__(16) unsigned short ks[2][64 * 192];
  __shared__ float redm[16][4], reds[16][4];
  int b = blockIdx.y, c0 = blockIdx.x * 16;
  int h0 = blockIdx.z * 12;
  float* outp = blockIdx.z ? p1 : p0;
  int t = threadIdx.x, lane = t & 63, wv = t >> 6;
  float macc[8][4];
#pragma unroll
  for (int f = 0; f < 8; ++f)
#pragma unroll
    for (int j = 0; j < 4; ++j) macc[f][j] = 0.f;
  int arow = lane & 15, asw = (arow & 7) << 3, ko = (lane >> 4) * 8;
  int brow = wv * 16 + (lane & 15), bsw = (brow & 7) << 3;
  for (int h = h0; h < h0 + 12; ++h) {
    size_t qbase = (size_t)(b * CL + c0) * E2 + h * HD;
    size_t kbase = (size_t)(b * CL) * E2 + h * HD;
    {
      int r = t / 24, s0 = t % 24;
      gload16(qh + qbase + (size_t)r * E2 + (s0 ^ (r & 7)) * 8, &qs[(wv * 64) * 8]);
      if (t < 128) {
        int ch2 = 256 + t, r2 = ch2 / 24, s2 = ch2 % 24;
        gload16(qh + qbase + (size_t)r2 * E2 + (s2 ^ (r2 & 7)) * 8,
                &qs[(256 + wv * 64) * 8]);
      }
#pragma unroll
      for (int i = 0; i < 6; ++i) {
        int chk = i * 256 + t, rk = chk / 24, sk = chk % 24;
        gload16(kh + kbase + (size_t)rk * E2 + (sk ^ (rk & 7)) * 8,
                &ks[0][(i * 256 + wv * 64) * 8]);
      }
    }
    __syncthreads();
    bf16x8 af[6];
#pragma unroll
    for (int ks_ = 0; ks_ < 6; ++ks_)
      af[ks_] = *(const bf16x8*)&qs[arow * 192 + ((ks_ * 32 + ko) ^ asw)];
    f32x4 acc[8];
#pragma unroll
    for (int f = 0; f < 8; ++f) acc[f] = (f32x4){0.f, 0.f, 0.f, 0.f};
#pragma unroll 1
    for (int hf = 0; hf < 8; ++hf) {
      if (hf < 7) {
        int base = (hf + 1) * 64;
#pragma unroll
        for (int i = 0; i < 6; ++i) {
          int chk = i * 256 + t, rk = chk / 24, sk = chk % 24;
          gload16(kh + kbase + (size_t)(base + rk) * E2 + (sk ^ (rk & 7)) * 8,
                  &ks[(hf + 1) & 1][(i * 256 + wv * 64) * 8]);
        }
      }
      const unsigned short* kb = ks[hf & 1];
#pragma unroll
      for (int ks_ = 0; ks_ < 6; ++ks_) {
        bf16x8 bg = *(const bf16x8*)&kb[brow * 192 + ((ks_ * 32 + ko) ^ bsw)];
        switch (hf) {
          case 0: acc[0] = __builtin_amdgcn_mfma_f32_16x16x32_bf16(af[ks_], bg, acc[0], 0, 0, 0); break;
          case 1: acc[1] = __builtin_amdgcn_mfma_f32_16x16x32_bf16(af[ks_], bg, acc[1], 0, 0, 0); break;
          case 2: acc[2] = __builtin_amdgcn_mfma_f32_16x16x32_bf16(af[ks_], bg, acc[2], 0, 0, 0); break;
          case 3: acc[3] = __builtin_amdgcn_mfma_f32_16x16x32_bf16(af[ks_], bg, acc[3], 0, 0, 0); break;
          case 4: acc[4] = __builtin_amdgcn_mfma_f32_16x16x32_bf16(af[ks_], bg, acc[4], 0, 0, 0); break;
          case 5: acc[5] = __builtin_amdgcn_mfma_f32_16x16x32_bf16(af[ks_], bg, acc[5], 0, 0, 0); break;
          case 6: acc[6] = __builtin_amdgcn_mfma_f32_16x16x32_bf16(af[ks_], bg, acc[6], 0, 0, 0); break;
          case 7: acc[7] = __builtin_amdgcn_mfma_f32_16x16x32_bf16(af[ks_], bg, acc[7], 0, 0, 0); break;
        }
      }
      __syncthreads();
    }
    float mx[4];
#pragma unroll
    for (int j = 0; j < 4; ++j) {
      float m = acc[0][j];
#pragma unroll
      for (int f = 1; f < 8; ++f) m = fmaxf(m, acc[f][j]);
#pragma unroll
      for (int msk = 1; msk < 16; msk <<= 1) m = fmaxf(m, __shfl_xor(m, msk, 64));
      mx[j] = m;
    }
    if ((lane & 15) == 0) {
#pragma unroll
      for (int j = 0; j < 4; ++j) redm[(lane >> 4) * 4 + j][wv] = mx[j];
    }
    __syncthreads();
    float Mj[4], sm[4];
#pragma unroll
    for (int j = 0; j < 4; ++j) {
      int r = (lane >> 4) * 4 + j;
      Mj[j] = fmaxf(fmaxf(redm[r][0], redm[r][1]), fmaxf(redm[r][2], redm[r][3]));
      sm[j] = 0.f;
    }
#pragma unroll
    for (int f = 0; f < 8; ++f)
#pragma unroll
      for (int j = 0; j < 4; ++j) {
        float e = expf((acc[f][j] - Mj[j]) * SCALE);
        acc[f][j] = e;
        sm[j] += e;
      }
#pragma unroll
    for (int j = 0; j < 4; ++j)
#pragma unroll
      for (int msk = 1; msk < 16; msk <<= 1) sm[j] += __shfl_xor(sm[j], msk, 64);
    if ((lane & 15) == 0) {
#pragma unroll
      for (int j = 0; j < 4; ++j) reds[(lane >> 4) * 4 + j][wv] = sm[j];
    }
    __syncthreads();
#pragma unroll
    for (int j = 0; j < 4; ++j) {
      int r = (lane >> 4) * 4 + j;
      float S = reds[r][0] + reds[r][1] + reds[r][2] + reds[r][3];
      float inv = 1.f / (S * 24.f);
#pragma unroll
      for (int f = 0; f < 8; ++f) macc[f][j] += acc[f][j] * inv;
    }
  }
#pragma unroll
  for (int f = 0; f < 8; ++f)
#pragma unroll
    for (int j = 0; j < 4; ++j) {
      int r = c0 + (lane >> 4) * 4 + j;
      int col = f * 64 + wv * 16 + (lane & 15);
      outp[(size_t)(b * CL + r) * CL + col] = macc[f][j];
    }
}

// ss = p0+p1; masked softmax over c (512 rows) per (b,d-col); bf16 out.
__global__ __launch_bounds__(256) void k_colsm2bf(
    const float* __restrict__ p0, const float* __restrict__ p1,
    const int* __restrict__ cmask, unsigned short* __restrict__ ob) {
  int b = blockIdx.y;
  int t = threadIdx.x, lane = t & 63, wv = t >> 6;
  int col = blockIdx.x * 16 + (lane & 15);
  int rsub = lane >> 4;
  __shared__ float rm[4][16], rs[4][16];
  const float* q0 = p0 + (size_t)b * CL * CL + col;
  const float* q1 = p1 + (size_t)b * CL * CL + col;
  const int* mp = cmask + b * CL;
  float m = NEGV;
  for (int it = 0; it < 32; ++it) {
    int r = wv * 128 + rsub + it * 4;
    float v = mp[r] ? (q0[(size_t)r * CL] + q1[(size_t)r * CL]) : NEGV;
    m = fmaxf(m, v);
  }
  m = fmaxf(m, __shfl_xor(m, 16, 64));
  m = fmaxf(m, __shfl_xor(m, 32, 64));
  if (lane < 16) rm[wv][lane] = m;
  __syncthreads();
  float M = fmaxf(fmaxf(rm[0][lane & 15], rm[1][lane & 15]),
                  fmaxf(rm[2][lane & 15], rm[3][lane & 15]));
  float s = 0.f;
  for (int it = 0; it < 32; ++it) {
    int r = wv * 128 + rsub + it * 4;
    float v = mp[r] ? (q0[(size_t)r * CL] + q1[(size_t)r * CL]) : NEGV;
    s += expf(v - M);
  }
  s += __shfl_xor(s, 16, 64);
  s += __shfl_xor(s, 32, 64);
  if (lane < 16) rs[wv][lane] = s;
  __syncthreads();
  float S = rs[0][lane & 15] + rs[1][lane & 15] + rs[2][lane & 15] + rs[3][lane & 15];
  float inv = 1.f / S;
  unsigned short* op = ob + (size_t)b * CL * CL + col;
  for (int it = 0; it < 32; ++it) {
    int r = wv * 128 + rsub + it * 4;
    float v = mp[r] ? (q0[(size_t)r * CL] + q1[(size_t)r * CL]) : NEGV;
    op[(size_t)r * CL] = f2bf(expf(v - M) * inv);
  }
}

// bf16 MFMA NN GEMM: out[b,c,e] += sum_d ss1b[b,c,d] * ybf[b,d,e].
__global__ __launch_bounds__(256) void k_gemm_nn(
    const unsigned short* __restrict__ A, const unsigned short* __restrict__ Bm,
    float* __restrict__ out) {
  __shared__ __align__(16) unsigned short As[128 * 64];
  __shared__ __align__(16) unsigned short Bs[128 * 64];
  int b = blockIdx.z;
  int n0 = blockIdx.x * 128, m0 = blockIdx.y * 128;
  int t = threadIdx.x, lane = t & 63, wv = t >> 6;
  int wr = wv >> 1, wc = wv & 1;
  f32x4 acc[4][4];
#pragma unroll
  for (int i = 0; i < 4; ++i)
#pragma unroll
    for (int j = 0; j < 4; ++j) acc[i][j] = (f32x4){0.f, 0.f, 0.f, 0.f};
  int sA = ((lane & 7) ^ ((lane >> 3) & 7)) * 8;
  int bd = (t & 31) * 2, be = (t >> 5) * 16;
  int arow = wr * 64 + (lane & 15), brow = wc * 64 + (lane & 15);
  int ko = (lane >> 4) * 8, asw = (lane & 7) << 3;
  unsigned* bs32 = (unsigned*)Bs;
  for (int k0 = 0; k0 < CL; k0 += 64) {
#pragma unroll
    for (int i = 0; i < 4; ++i) {
      int chunk = wv * 4 + i, row = chunk * 8 + (lane >> 3);
      gload16(A + (size_t)(b * CL + m0 + row) * CL + k0 + sA, &As[chunk * 512]);
    }
    {
      const unsigned short* bp = Bm + (size_t)(b * CL + k0 + bd) * E2 + n0 + be;
      uint4 ra = *(const uint4*)bp;
      uint4 rb = *(const uint4*)(bp + 8);
      uint4 rc = *(const uint4*)(bp + E2);
      uint4 rd = *(const uint4*)(bp + E2 + 8);
      unsigned a0[4] = {ra.x, ra.y, ra.z, ra.w};
      unsigned c0_[4] = {rc.x, rc.y, rc.z, rc.w};
      unsigned a1[4] = {rb.x, rb.y, rb.z, rb.w};
      unsigned c1[4] = {rd.x, rd.y, rd.z, rd.w};
#pragma unroll
      for (int j = 0; j < 8; ++j) {
        int e = be + j;
        unsigned lo = (a0[j >> 1] >> ((j & 1) * 16)) & 0xffffu;
        unsigned hi = (c0_[j >> 1] >> ((j & 1) * 16)) & 0xffffu;
        bs32[e * 32 + ((bd >> 1) ^ ((e & 7) << 2))] = lo | (hi << 16);
      }
#pragma unroll
      for (int j = 0; j < 8; ++j) {
        int e = be + 8 + j;
        unsigned lo = (a1[j >> 1] >> ((j & 1) * 16)) & 0xffffu;
        unsigned hi = (c1[j >> 1] >> ((j & 1) * 16)) & 0xffffu;
        bs32[e * 32 + ((bd >> 1) ^ ((e & 7) << 2))] = lo | (hi << 16);
      }
    }
    __syncthreads();
#pragma unroll
    for (int ks_ = 0; ks_ < 2; ++ks_) {
      bf16x8 af[4], bg[4];
#pragma unroll
      for (int mi = 0; mi < 4; ++mi)
        af[mi] = *(const bf16x8*)&As[(arow + mi * 16) * 64 + ((ks_ * 32 + ko) ^ asw)];
#pragma unroll
      for (int ni = 0; ni < 4; ++ni)
        bg[ni] = *(const bf16x8*)&Bs[(brow + ni * 16) * 64 + ((ks_ * 32 + ko) ^ asw)];
#pragma unroll
      for (int mi = 0; mi < 4; ++mi)
#pragma unroll
        for (int ni = 0; ni < 4; ++ni)
          acc[mi][ni] = __builtin_amdgcn_mfma_f32_16x16x32_bf16(
              af[mi], bg[ni], acc[mi][ni], 0, 0, 0);
    }
    __syncthreads();
  }
#pragma unroll
  for (int mi = 0; mi < 4; ++mi)
#pragma unroll
    for (int ni = 0; ni < 4; ++ni) {
      int row = m0 + wr * 64 + mi * 16 + (lane >> 4) * 4;
      int col = n0 + wc * 64 + ni * 16 + (lane & 15);
#pragma unroll
      for (int j = 0; j < 4; ++j) {
        size_t idx = (size_t)(b * CL + row + j) * E2 + col;
        out[idx] += acc[mi][ni][j];
      }
    }
}

// concat x -> d_out; layernorm -> ybf (bf16).
__global__ __launch_bounds__(256) void k_xln(
    const float* __restrict__ c, const float* __restrict__ a,
    const float* __restrict__ bf, const float* __restrict__ s3,
    const float* __restrict__ ac, const float* __restrict__ gamma,
    const float* __restrict__ beta, float* __restrict__ xout,
    unsigned short* __restrict__ ybf) {
  int row = blockIdx.x, t = threadIdx.x, lane = t & 63, wv = t >> 6;
  size_t base = (size_t)row * H_;
  float xs[6][3];
  float sum = 0.f, sq = 0.f;
#pragma unroll
  for (int kk = 0; kk < 3; ++kk) {
    int j = t + kk * 256;
    float cv = c[base + j], av = a[base + j], bv = bf[base + j];
    float sv = s3[base + j], av2 = ac[base + j];
    xs[0][kk] = cv; xs[1][kk] = av; xs[2][kk] = cv * av;
    xs[3][kk] = cv * bv; xs[4][kk] = sv; xs[5][kk] = av2;
  }
#pragma unroll
  for (int s = 0; s < 6; ++s)
#pragma unroll
    for (int kk = 0; kk < 3; ++kk) {
      sum += xs[s][kk];
      sq += xs[s][kk] * xs[s][kk];
    }
  sum = wave_sum(sum);
  sq = wave_sum(sq);
  __shared__ float red[4][2];
  if (lane == 0) { red[wv][0] = sum; red[wv][1] = sq; }
  __syncthreads();
  float TS = red[0][0] + red[1][0] + red[2][0] + red[3][0];
  float TQ = red[0][1] + red[1][1] + red[2][1] + red[3][1];
  float mu = TS * (1.f / (float)E2);
  float var = TQ * (1.f / (float)E2) - mu * mu;
  float rstd = rsqrtf(var + 1e-5f);
  size_t obase = (size_t)row * E2;
#pragma unroll
  for (int s = 0; s < 6; ++s)
#pragma unroll
    for (int kk = 0; kk < 3; ++kk) {
      int col = s * H_ + t + kk * 256;
      float xv = xs[s][kk];
      float yv = (xv - mu) * rstd * gamma[col] + beta[col];
      xout[obase + col] = xv;
      ybf[obase + col] = f2bf(yv);
    }
}

extern "C" void kernel_launch(void* const* d_in, const int* in_sizes, int n_in,
                              void* d_out, int out_size, void* d_ws,
                              size_t ws_size, hipStream_t stream) {
  const float* c = (const float*)d_in[0];
  const float* q = (const float*)d_in[1];
  const int* c_mask = (const int*)d_in[2];
  const int* q_mask = (const int*)d_in[3];
  const float* c_weight = (const float*)d_in[4];
  const float* q_weight = (const float*)d_in[5];
  const float* cq_weight = (const float*)d_in[6];
  const float* bias = (const float*)d_in[7];
  const float* wq1 = (const float*)d_in[8];
  const float* bq1 = (const float*)d_in[9];
  const float* wk1 = (const float*)d_in[10];
  const float* bk1 = (const float*)d_in[11];
  const float* gamma = (const float*)d_in[12];
  const float* beta = (const float*)d_in[13];
  const float* wq2 = (const float*)d_in[14];
  const float* bq2 = (const float*)d_in[15];
  const float* wk2 = (const float*)d_in[16];
  const float* bk2 = (const float*)d_in[17];
  float* out = (float*)d_out;

  // ---- workspace (bytes): persistent 193.2MB; early fp32 bufs aliased. ----
  char* wsb = (char*)d_ws;
  unsigned short* ybf  = (unsigned short*)wsb;                   // 37,748,736
  unsigned short* qh2b = (unsigned short*)(wsb + 37748736);      // 37,748,736
  unsigned short* kh2b = (unsigned short*)(wsb + 75497472);      // 37,748,736
  unsigned short* wbf  = (unsigned short*)(wsb + 113246208);     // 42,467,328
  float* p0   = (float*)(wsb + 155713536);                       //  8,388,608
  float* p1   = (float*)(wsb + 164102144);                       //  8,388,608
  unsigned short* ss1b = (unsigned short*)(wsb + 172490752);     //  4,194,304
  unsigned short* cb   = (unsigned short*)(wsb + 176685056);     //  6,291,456
  unsigned short* qb   = (unsigned short*)(wsb + 182976512);     //    786,432
  unsigned short* w1qb = (unsigned short*)(wsb + 183762944);     //  1,179,648
  unsigned short* w1kb = (unsigned short*)(wsb + 184942592);     //  1,179,648
  unsigned short* qh1b = (unsigned short*)(wsb + 186122240);     //  6,291,456
  unsigned short* kh1b = (unsigned short*)(wsb + 192413696);     //    786,432
  // early fp32 buffers (dead before stage 16) alias [qh2b..) region:
  float* e = (float*)(wsb + 37748736);
  float* s      = e; e += 262144;
  float* s1m    = e; e += 262144;
  float* s2m    = e; e += 262144;
  float* scoatb = e; e += 262144;
  float* scoat1 = e; e += 262144;
  float* scoat2 = e; e += 262144;
  float* s0buf  = e; e += 4096;
  float* s1buf  = e; e += 512;
  float* U_     = e; e += 393216;
  float* bcoat  = e; e += 393216;
  float* a_     = e; e += 3145728;
  float* bfull  = e; e += 3145728;
  float* acoat  = e; e += 3145728;
  float* scoat3 = e; e += 3145728;

  // 1. s0, s1 row dots
  k_rowdot<<<B_ * CL / 4, 256, 0, stream>>>(c, c_weight, s0buf, H_);
  k_rowdot<<<B_ * QL / 4, 256, 0, stream>>>(q, q_weight, s1buf, H_);
  // 2. s
  k_s_assemble<<<dim3(CL / 32, B_), 256, 0, stream>>>(c, q, cq_weight, s0buf,
                                                      s1buf, bias, s);
  // 3-4. masked softmaxes
  k_rowsm64<<<B_ * CL / 4, 256, 0, stream>>>(s, q_mask, s1m);
  k_colsm<<<dim3(QL, B_), 256, 0, stream>>>(s, c_mask, s2m, QL);
  // 5-7. a, U = s2m^T@c, b = s1m@U
  k_gemm_bt<<<dim3(H_ / 64, CL / 32, B_), 256, 0, stream>>>(s1m, q, a_, CL, QL, H_, 0, 0);
  k_gemm_bt<<<dim3(H_ / 64, QL / 32, B_), 256, 0, stream>>>(s2m, c, U_, QL, CL, H_, 1, 0);
  k_gemm_bt<<<dim3(H_ / 64, CL / 32, B_), 256, 0, stream>>>(s1m, U_, bfull, CL, QL, H_, 0, 0);
  // 8. casts + qh1b/kh1b via bf16 MFMA 2-phase GEMM
  k_cast4<<<2304, 256, 0, stream>>>(c, cb, 1536, q, qb, 192, wq1, w1qb, 288,
                                    wk1, w1kb);
  k_gemm_2ph<<<dim3(H_ / 128, B_ * CL / 128), 256, 0, stream>>>(cb, w1qb, bq1,
                                                                qh1b, H_, H_);
  k_gemm_2ph<<<dim3(H_ / 128, B_ * QL / 128), 256, 0, stream>>>(qb, w1kb, bk1,
                                                                kh1b, H_, H_);
  // 9-11. scoat (LDS-staged bf16 mha) + masked softmaxes
  k_mha1b<<<dim3(CL / 16, B_), 256, 0, stream>>>(qh1b, kh1b, scoatb);
  k_rowsm64<<<B_ * CL / 4, 256, 0, stream>>>(scoatb, q_mask, scoat1);
  k_colsm<<<dim3(QL, B_), 256, 0, stream>>>(scoatb, c_mask, scoat2, QL);
  // 12-14. acoat, bcoat, scoat3
  k_gemm_bt<<<dim3(H_ / 64, CL / 32, B_), 256, 0, stream>>>(scoat1, q, acoat, CL, QL, H_, 0, 0);
  k_gemm_bt<<<dim3(H_ / 64, QL / 32, B_), 256, 0, stream>>>(scoat2, c, bcoat, QL, CL, H_, 1, 0);
  k_gemm_bt<<<dim3(H_ / 64, CL / 32, B_), 256, 0, stream>>>(scoat1, bcoat, scoat3, CL, QL, H_, 0, 0);
  // 15. x (-> d_out) + layernorm -> ybf
  k_xln<<<B_ * CL, 256, 0, stream>>>(c, a_, bfull, scoat3, acoat, gamma, beta,
                                     out, ybf);
  // 16. casts + big bf16 MFMA 2-phase GEMMs
  k_cast<<<E2 * E2 / 2048, 256, 0, stream>>>(wq2, wbf);
  k_gemm_2ph<<<dim3(E2 / 128, B_ * CL / 128), 256, 0, stream>>>(ybf, wbf, bq2,
                                                                qh2b, E2, E2);
  k_cast<<<E2 * E2 / 2048, 256, 0, stream>>>(wk2, wbf);
  k_gemm_2ph<<<dim3(E2 / 128, B_ * CL / 128), 256, 0, stream>>>(ybf, wbf, bk2,
                                                                kh2b, E2, E2);
  // 17. 24-head scores via MFMA (head-split partials)
  k_ssm<<<dim3(CL / 16, B_, 2), 256, 0, stream>>>(qh2b, kh2b, p0, p1);
  // 18. ss = p0+p1 -> masked col softmax -> ss1b (bf16)
  k_colsm2bf<<<dim3(CL / 16, B_), 256, 0, stream>>>(p0, p1, c_mask, ss1b);
  // 19. patt = ss1b @ ybf + x (x already in d_out)
  k_gemm_nn<<<dim3(E2 / 128, CL / 128, B_), 256, 0, stream>>>(ss1b, ybf, out);
}